// Round 6
// baseline (473.673 us; speedup 1.0000x reference)
//
#include <hip/hip_runtime.h>
#include <hip/hip_bf16.h>

// Problem constants (fixed by the reference)
#define BB 8
#define CC 512
#define TT 4096
#define HH 8
#define DH 64
#define EPS 1e-6f

#define NROWS (BB * TT)          // 32768 flat (b,t) rows

using bf16x8 = __attribute__((ext_vector_type(8))) short;
using s16x4  = __attribute__((ext_vector_type(4))) short;
using f32x4  = __attribute__((ext_vector_type(4))) float;

__device__ __forceinline__ short f2b(float f) {
  __hip_bfloat16 h = __float2bfloat16(f);   // HW RNE (compiler can pack cvt_pk)
  return *reinterpret_cast<short*>(&h);
}
__device__ __forceinline__ float b2f(short s) {
  unsigned u = ((unsigned)(unsigned short)s) << 16;
  return __uint_as_float(u);
}

// async global->LDS 16B copy (dest must be wave-uniform base + lane*16)
__device__ __forceinline__ void gld16(short* lds_dst, const short* gsrc) {
  __builtin_amdgcn_global_load_lds(
      (const __attribute__((address_space(1))) unsigned int*)gsrc,
      (__attribute__((address_space(3))) unsigned int*)lds_dst, 16, 0, 0);
}

// W fp32 [o][c] -> bf16 [o][c]
__global__ __launch_bounds__(256) void conv_w(const float* __restrict__ src,
                                              short* __restrict__ dst)
{
  int i8 = (blockIdx.x * 256 + threadIdx.x) * 8;
  float4 a = *(const float4*)(src + i8);
  float4 b = *(const float4*)(src + i8 + 4);
  bf16x8 h = { f2b(a.x), f2b(a.y), f2b(a.z), f2b(a.w),
               f2b(b.x), f2b(b.y), f2b(b.z), f2b(b.w) };
  *(bf16x8*)(dst + i8) = h;
}

// ---------------------------------------------------------------------------
// transpose+convert: X fp32 [b][c][t] -> Xt bf16 [b][t][c]
// grid (T/64, C/64, B), 256 thr, 64x64 LDS tile (stride 68 shorts).
// ---------------------------------------------------------------------------
__global__ __launch_bounds__(256) void transpose_cvt(const float* __restrict__ X,
                                                     short* __restrict__ Xt)
{
  __shared__ short tile[64 * 68];
  const int t0 = blockIdx.x * 64, c0 = blockIdx.y * 64, b = blockIdx.z;
  const int tid = threadIdx.x;
  // phase A: read rows of X (coalesced float4), write tile[c][t]
  {
    int cl = tid >> 4, t4 = (tid & 15) * 4;
    #pragma unroll
    for (int it = 0; it < 4; ++it) {
      int c = it * 16 + cl;
      float4 v = *(const float4*)(X + ((size_t)b * CC + c0 + c) * TT + t0 + t4);
      s16x4 h = { f2b(v.x), f2b(v.y), f2b(v.z), f2b(v.w) };
      *(s16x4*)&tile[c * 68 + t4] = h;
    }
  }
  __syncthreads();
  // phase B: read tile columns, write rows of Xt (coalesced b128)
  {
    int t = tid >> 2, ci = (tid & 3) * 16;
    short s[16];
    #pragma unroll
    for (int i = 0; i < 16; ++i) s[i] = tile[(ci + i) * 68 + t];
    short* dst = Xt + ((size_t)b * TT + t0 + t) * CC + c0 + ci;
    *(bf16x8*)dst = *(bf16x8*)&s[0];
    *(bf16x8*)(dst + 8) = *(bf16x8*)&s[8];
  }
}

// ---------------------------------------------------------------------------
// GEMM (pure bf16, both K-contig): Y[m][o] = sum_c A[m][c] * W[o][c] + bias[o]
// A = [NROWS][512] bf16, W = [512][512] bf16. 128x128 tile, BK=32, 4 waves.
// m97 structure: global_load_lds(16) both tiles; XCD-chunked block swizzle.
// ---------------------------------------------------------------------------
__global__ __launch_bounds__(256) void gemm_tc(const short* __restrict__ A,
                                               const short* __restrict__ W,
                                               const float* __restrict__ bias,
                                               short* __restrict__ Y)
{
  __shared__ short As[128 * 32];
  __shared__ short Bs[128 * 32];
  const int tid = threadIdx.x;
  // swizzle: 1024 blocks -> each XCD owns a contiguous chunk of m-tiles
  int x = blockIdx.x;
  int wg = (x & 7) * 128 + (x >> 3);
  const int m0 = (wg >> 2) * 128;          // 256 m-tiles
  const int o0 = (wg & 3) * 128;           // 4 o-tiles

  const int wid = tid >> 6, lane = tid & 63;
  const int wr = (wid >> 1) * 64, wc = (wid & 1) * 64;
  const int lr = lane & 15, lk8 = (lane >> 4) * 8;

  f32x4 acc[4][4] = {};

  for (int k0 = 0; k0 < CC; k0 += 32) {
    #pragma unroll
    for (int it = 0; it < 2; ++it) {
      int off = it * 4096 + tid * 16;      // bytes within 8KB tile
      int row = off >> 6, col = (off & 63) >> 1;
      gld16(As + (off >> 1), A + (size_t)(m0 + row) * CC + k0 + col);
      gld16(Bs + (off >> 1), W + (size_t)(o0 + row) * CC + k0 + col);
    }
    __syncthreads();
    bf16x8 af[4], bf[4];
    #pragma unroll
    for (int m = 0; m < 4; ++m) af[m] = *(const bf16x8*)&As[(wr + m * 16 + lr) * 32 + lk8];
    #pragma unroll
    for (int n = 0; n < 4; ++n) bf[n] = *(const bf16x8*)&Bs[(wc + n * 16 + lr) * 32 + lk8];
    #pragma unroll
    for (int m = 0; m < 4; ++m)
      #pragma unroll
      for (int n = 0; n < 4; ++n)
        acc[m][n] = __builtin_amdgcn_mfma_f32_16x16x32_bf16(af[m], bf[n], acc[m][n], 0, 0, 0);
    __syncthreads();
  }

  const int lq4 = (lane >> 4) * 4;
  #pragma unroll
  for (int m = 0; m < 4; ++m)
    #pragma unroll
    for (int r = 0; r < 4; ++r) {
      size_t row = (size_t)(m0 + wr + m * 16 + lq4 + r) * CC;
      #pragma unroll
      for (int n = 0; n < 4; ++n) {
        int o = o0 + wc + n * 16 + lr;
        Y[row + o] = f2b(acc[m][n][r] + bias[o]);
      }
    }
}

// ---------------------------------------------------------------------------
// Row feature kernels on [row][512] bf16, wave per row, in-place.
// MODE: 0=Q (rms->elu+1->per-head softmax->*8^-0.5), 1=K (rms->elu+1),
//       2=V (rms->elu+1->/64)
// ---------------------------------------------------------------------------
template<int MODE>
__global__ __launch_bounds__(256) void feat_row(short* __restrict__ buf,
                                                const float* __restrict__ g)
{
  const int row = blockIdx.x * 4 + (threadIdx.x >> 6);
  const int lane = threadIdx.x & 63;
  short* p = buf + (size_t)row * CC + lane * 8;
  bf16x8 v = *(const bf16x8*)p;
  float x[8], ss = 0.f;
  #pragma unroll
  for (int j = 0; j < 8; ++j) { x[j] = b2f(v[j]); ss += x[j] * x[j]; }
  #pragma unroll
  for (int off = 32; off; off >>= 1) ss += __shfl_xor(ss, off);
  float rn = rsqrtf(ss * (1.0f / CC) + EPS);
  float4 g0 = *(const float4*)(g + lane * 8);
  float4 g1 = *(const float4*)(g + lane * 8 + 4);
  float gv[8] = { g0.x, g0.y, g0.z, g0.w, g1.x, g1.y, g1.z, g1.w };
  float f[8];
  #pragma unroll
  for (int j = 0; j < 8; ++j) {
    float t = x[j] * rn * gv[j];
    f[j] = t > 0.f ? t + 1.f : __expf(t);
  }
  bf16x8 o;
  if constexpr (MODE == 1) {
    #pragma unroll
    for (int j = 0; j < 8; ++j) o[j] = f2b(f[j]);
  } else if constexpr (MODE == 2) {
    #pragma unroll
    for (int j = 0; j < 8; ++j) o[j] = f2b(f[j] * (1.0f / DH));
  } else {  // Q: softmax over head (64 c = 8 lanes), no max-sub (f <= ~24)
    float ls = 0.f;
    #pragma unroll
    for (int j = 0; j < 8; ++j) { f[j] = __expf(f[j]); ls += f[j]; }
    ls += __shfl_xor(ls, 1); ls += __shfl_xor(ls, 2); ls += __shfl_xor(ls, 4);
    float sc = 0.35355339059327373f / ls;     // 8^-0.5 / sum
    #pragma unroll
    for (int j = 0; j < 8; ++j) o[j] = f2b(f[j] * sc);
  }
  *(bf16x8*)p = o;
}

// ---------------------------------------------------------------------------
// k time-softmax (no max-sub: values <= ~24, exp fits fp32; mask -> 0)
// ---------------------------------------------------------------------------
__global__ __launch_bounds__(256) void ksm_sum(const short* __restrict__ kf,
                                               const unsigned char* __restrict__ mask,
                                               float* __restrict__ S)
{
  const int b = blockIdx.y, t0 = blockIdx.x * 64;
  const int c2 = threadIdx.x * 2;
  const unsigned char* mk = mask + (size_t)b * TT + t0;
  float s0 = 0.f, s1 = 0.f;
  for (int t = 0; t < 64; ++t) {
    if (mk[t]) continue;
    unsigned u = *(const unsigned*)&kf[((size_t)b * TT + t0 + t) * CC + c2];
    s0 += __expf(__uint_as_float(u << 16));
    s1 += __expf(__uint_as_float(u & 0xffff0000u));
  }
  atomicAdd(&S[b * CC + c2], s0);
  atomicAdd(&S[b * CC + c2 + 1], s1);
}

__global__ __launch_bounds__(256) void ksm_apply(short* __restrict__ kf,
                                                 const unsigned char* __restrict__ mask,
                                                 const float* __restrict__ S)
{
  const int b = blockIdx.y, t0 = blockIdx.x * 64;
  const int c2 = threadIdx.x * 2;
  const unsigned char* mk = mask + (size_t)b * TT + t0;
  const float i0 = 1.f / S[b * CC + c2];
  const float i1 = 1.f / S[b * CC + c2 + 1];
  for (int t = 0; t < 64; ++t) {
    unsigned* p = (unsigned*)&kf[((size_t)b * TT + t0 + t) * CC + c2];
    if (mk[t]) { *p = 0u; continue; }
    unsigned u = *p;
    float y0 = __expf(__uint_as_float(u << 16)) * i0;
    float y1 = __expf(__uint_as_float(u & 0xffff0000u)) * i1;
    *p = ((unsigned)(unsigned short)f2b(y0)) | (((unsigned)(unsigned short)f2b(y1)) << 16);
  }
}

// ---------------------------------------------------------------------------
// ctx partials from t-major kf/vf: P[tc][bh][q][v] = sum_t kf[t][q]*vf[t][v]
// grid (8 t-chunks of 512, 64 bh), 256 thr. LDS [64t][64c] tiles, gload_lds.
// A-frag/B-frag via scalar column reads (HBM-bound kernel, LDS cost hidden).
// ---------------------------------------------------------------------------
__global__ __launch_bounds__(256) void ctx_t(const short* __restrict__ kf,
                                             const short* __restrict__ vf,
                                             float* __restrict__ P)
{
  __shared__ short Ks[64 * 64];
  __shared__ short Vs[64 * 64];
  const int tc = blockIdx.x, bh = blockIdx.y;
  const int b = bh >> 3, h = bh & 7;
  const int tid = threadIdx.x, wid = tid >> 6, lane = tid & 63;
  const int lr = lane & 15, lg = lane >> 4;
  f32x4 acc[4] = {};

  for (int ts = 0; ts < 8; ++ts) {
    #pragma unroll
    for (int i = 0; i < 2; ++i) {
      int n = i * 256 + tid;               // 512 chunks of 16B
      int t = n >> 3, ch = (n & 7) * 8;
      size_t src = ((size_t)b * TT + tc * 512 + ts * 64 + t) * CC + h * DH + ch;
      gld16(Ks + n * 8, kf + src);
      gld16(Vs + n * 8, vf + src);
    }
    __syncthreads();
    #pragma unroll
    for (int kk = 0; kk < 64; kk += 32) {
      short a[8];
      #pragma unroll
      for (int j = 0; j < 8; ++j)
        a[j] = Ks[(kk + lg * 8 + j) * 64 + wid * 16 + lr];
      bf16x8 af = *(const bf16x8*)&a[0];
      #pragma unroll
      for (int n = 0; n < 4; ++n) {
        short bv[8];
        #pragma unroll
        for (int j = 0; j < 8; ++j)
          bv[j] = Vs[(kk + lg * 8 + j) * 64 + n * 16 + lr];
        acc[n] = __builtin_amdgcn_mfma_f32_16x16x32_bf16(af, *(const bf16x8*)&bv[0],
                                                         acc[n], 0, 0, 0);
      }
    }
    __syncthreads();
  }
  float* pp = P + ((size_t)tc * 64 + bh) * (DH * DH);
  const int lq4 = lg * 4;
  #pragma unroll
  for (int n = 0; n < 4; ++n)
    #pragma unroll
    for (int r = 0; r < 4; ++r)
      pp[(wid * 16 + lq4 + r) * DH + n * 16 + lr] = acc[n][r];
}

// reduce chunk partials, emit TRANSPOSED bf16 ctx: CT[bh][v][q]
__global__ __launch_bounds__(256) void ctx_reduce(const float* __restrict__ P, short* __restrict__ CT)
{
  int i = blockIdx.x * 256 + threadIdx.x;    // (bh, q, v), v fastest
  float s = 0.f;
  #pragma unroll
  for (int c = 0; c < 8; ++c) s += P[(size_t)c * 64 * DH * DH + i];
  int bh = i >> 12, rem = i & 4095, q = rem >> 6, v = rem & 63;
  CT[((size_t)bh << 12) + v * 64 + q] = f2b(s);
}

// ---------------------------------------------------------------------------
// attn: ao[row][h*64+v] = sum_q qf[row][h*64+q] * CT[bh][v][q]
// grid (256 m-tiles of 128 rows, 8 heads), 256 thr, reg-staged stride-72 LDS.
// ---------------------------------------------------------------------------
__global__ __launch_bounds__(256) void attn_t(const short* __restrict__ qf,
                                              const short* __restrict__ CT,
                                              short* __restrict__ ao)
{
  __shared__ short As[128 * 72];
  __shared__ short Cs[64 * 72];
  const int m0 = blockIdx.x * 128, h = blockIdx.y;
  const int tid = threadIdx.x, wid = tid >> 6, lane = tid & 63;
  const int lr = lane & 15, lk8 = (lane >> 4) * 8;

  #pragma unroll
  for (int i = 0; i < 4; ++i) {
    int n = i * 256 + tid;                 // 1024 chunks
    int r = n >> 3, ch = (n & 7) * 8;
    *(bf16x8*)&As[r * 72 + ch] =
        *(const bf16x8*)(qf + (size_t)(m0 + r) * CC + h * DH + ch);
  }
  {
    const int bh0 = (m0 / TT) * 8 + h;     // batch of this m-tile (tiles don't cross b)
    #pragma unroll
    for (int i = 0; i < 2; ++i) {
      int n = i * 256 + tid;               // 512 chunks
      int v = n >> 3, ch = (n & 7) * 8;
      *(bf16x8*)&Cs[v * 72 + ch] = *(const bf16x8*)(CT + ((size_t)bh0 << 12) + v * 64 + ch);
    }
  }
  __syncthreads();

  const int wr = wid * 32;
  f32x4 acc[2][4] = {};
  #pragma unroll
  for (int kk = 0; kk < 64; kk += 32) {
    bf16x8 af[2], cf[4];
    #pragma unroll
    for (int m = 0; m < 2; ++m) af[m] = *(const bf16x8*)&As[(wr + m * 16 + lr) * 72 + kk + lk8];
    #pragma unroll
    for (int n = 0; n < 4; ++n) cf[n] = *(const bf16x8*)&Cs[(n * 16 + lr) * 72 + kk + lk8];
    #pragma unroll
    for (int m = 0; m < 2; ++m)
      #pragma unroll
      for (int n = 0; n < 4; ++n)
        acc[m][n] = __builtin_amdgcn_mfma_f32_16x16x32_bf16(af[m], cf[n], acc[m][n], 0, 0, 0);
  }
  const int lq4 = (lane >> 4) * 4;
  #pragma unroll
  for (int m = 0; m < 2; ++m)
    #pragma unroll
    for (int r = 0; r < 4; ++r) {
      size_t row = (size_t)(m0 + wr + m * 16 + lq4 + r) * CC + h * DH;
      #pragma unroll
      for (int n = 0; n < 4; ++n)
        ao[row + n * 16 + lr] = f2b(acc[m][n][r]);
    }
}

// ---------------------------------------------------------------------------
// final: rms over (pj + qt) rows, then scale + transposed write to d_out [c][t]
// ---------------------------------------------------------------------------
__global__ __launch_bounds__(256) void final_a(const short* __restrict__ pj,
                                               const short* __restrict__ qt,
                                               float* __restrict__ rms)
{
  const int row = blockIdx.x * 4 + (threadIdx.x >> 6);
  const int lane = threadIdx.x & 63;
  bf16x8 a = *(const bf16x8*)(pj + (size_t)row * CC + lane * 8);
  bf16x8 b = *(const bf16x8*)(qt + (size_t)row * CC + lane * 8);
  float ss = 0.f;
  #pragma unroll
  for (int j = 0; j < 8; ++j) { float z = b2f(a[j]) + b2f(b[j]); ss += z * z; }
  #pragma unroll
  for (int off = 32; off; off >>= 1) ss += __shfl_xor(ss, off);
  if (lane == 0) rms[row] = rsqrtf(ss * (1.0f / CC) + EPS);
}

__global__ __launch_bounds__(256) void final_b(const short* __restrict__ pj,
                                               const short* __restrict__ qt,
                                               const float* __restrict__ rms,
                                               const float* __restrict__ g,
                                               float* __restrict__ out)
{
  const int b = blockIdx.y, t0 = blockIdx.x * 64;
  const int tid = threadIdx.x;
  for (int i = 0; i < 16; ++i) {
    int flat = i * 256 + tid;              // 4096 = 64 t x 64 c-groups
    int t = flat >> 6, c8 = (flat & 63) * 8;
    size_t row = ((size_t)b * TT + t0 + t) * CC + c8;
    bf16x8 a = *(const bf16x8*)(pj + row);
    bf16x8 q = *(const bf16x8*)(qt + row);
    float r = rms[b * TT + t0 + t];
    float4 g0 = *(const float4*)(g + c8);
    float4 g1 = *(const float4*)(g + c8 + 4);
    float gv[8] = { g0.x, g0.y, g0.z, g0.w, g1.x, g1.y, g1.z, g1.w };
    #pragma unroll
    for (int j = 0; j < 8; ++j) {
      float z = (b2f(a[j]) + b2f(q[j])) * r * gv[j];
      out[((size_t)b * CC + c8 + j) * TT + t0 + t] = z;   // scattered 4B; L2 merges
    }
  }
}

// ---------------------------------------------------------------------------
extern "C" void kernel_launch(void* const* d_in, const int* in_sizes, int n_in,
                              void* d_out, int out_size, void* d_ws, size_t ws_size,
                              hipStream_t stream) {
  (void)in_sizes; (void)n_in; (void)out_size; (void)ws_size;
  const float* queries = (const float*)d_in[0];
  const float* keys    = (const float*)d_in[1];
  const float* values  = (const float*)d_in[2];
  const unsigned char* mask = (const unsigned char*)d_in[3];
  const float* Wq = (const float*)d_in[4];
  const float* bq = (const float*)d_in[5];
  const float* gq = (const float*)d_in[6];
  const float* Wk = (const float*)d_in[7];
  const float* bk = (const float*)d_in[8];
  const float* gk = (const float*)d_in[9];
  const float* Wv = (const float*)d_in[10];
  const float* bv = (const float*)d_in[11];
  const float* gv = (const float*)d_in[12];
  const float* Wp = (const float*)d_in[13];
  const float* bp = (const float*)d_in[14];
  const float* g_out = (const float*)d_in[15];

  const size_t NCT = (size_t)NROWS * CC;       // 16,777,216 elements
  short* qt = (short*)d_ws;                    // bf16 [row][c] transposed inputs
  short* kt = qt + NCT;
  short* vt = kt + NCT;
  short* qf = vt + NCT;                        // gemm outputs / features (in-place)
  short* kf = qf + NCT;
  short* vf = kf + NCT;
  short* ao = kt;                              // reuse (kt dead after its gemm)
  short* pj = vt;                              // reuse (vt dead after its gemm)
  float* ctxP = (float*)(vf + NCT);            // 8 x 64 x 4096 fp32
  short* CT  = (short*)(ctxP + (size_t)8 * 64 * DH * DH);   // [bh][v][q] bf16
  short* wqb = CT + (size_t)64 * DH * DH;
  short* wkb = wqb + (size_t)CC * CC;
  short* wvb = wkb + (size_t)CC * CC;
  short* wpb = wvb + (size_t)CC * CC;
  float* S   = (float*)(wpb + (size_t)CC * CC);   // [B][C] softmax sums
  float* rms = S + (size_t)BB * CC;               // [row]

  hipMemsetAsync(S, 0, (size_t)BB * CC * sizeof(float), stream);

  conv_w<<<dim3(CC * CC / 2048), 256, 0, stream>>>(Wq, wqb);
  conv_w<<<dim3(CC * CC / 2048), 256, 0, stream>>>(Wk, wkb);
  conv_w<<<dim3(CC * CC / 2048), 256, 0, stream>>>(Wv, wvb);
  conv_w<<<dim3(CC * CC / 2048), 256, 0, stream>>>(Wp, wpb);

  dim3 gT(TT / 64, CC / 64, BB);
  transpose_cvt<<<gT, 256, 0, stream>>>(queries, qt);
  transpose_cvt<<<gT, 256, 0, stream>>>(keys,    kt);
  transpose_cvt<<<gT, 256, 0, stream>>>(values,  vt);

  dim3 gG(1024);
  gemm_tc<<<gG, 256, 0, stream>>>(qt, wqb, bq, qf);
  gemm_tc<<<gG, 256, 0, stream>>>(kt, wkb, bk, kf);
  gemm_tc<<<gG, 256, 0, stream>>>(vt, wvb, bv, vf);

  feat_row<0><<<dim3(NROWS / 4), 256, 0, stream>>>(qf, gq);
  feat_row<1><<<dim3(NROWS / 4), 256, 0, stream>>>(kf, gk);
  feat_row<2><<<dim3(NROWS / 4), 256, 0, stream>>>(vf, gv);

  dim3 gS(TT / 64, BB);
  ksm_sum<<<gS, 256, 0, stream>>>(kf, mask, S);
  ksm_apply<<<gS, 256, 0, stream>>>(kf, mask, S);

  ctx_t<<<dim3(8, BB * HH), 256, 0, stream>>>(kf, vf, ctxP);
  ctx_reduce<<<dim3(64 * DH * DH / 256), 256, 0, stream>>>(ctxP, CT);

  attn_t<<<dim3(NROWS / 128, HH), 256, 0, stream>>>(qf, CT, ao);

  gemm_tc<<<gG, 256, 0, stream>>>(ao, wpb, bp, pj);

  final_a<<<dim3(NROWS / 4), 256, 0, stream>>>(pj, qt, rms);
  final_b<<<dim3(TT / 64, BB), 256, 0, stream>>>(pj, qt, rms, g_out, (float*)d_out);
}

// Round 7
// 362.562 us; speedup vs baseline: 1.3065x; 1.3065x over previous
//
#include <hip/hip_runtime.h>
#include <hip/hip_bf16.h>

// Problem constants (fixed by the reference)
#define BB 8
#define CC 512
#define TT 4096
#define HH 8
#define DH 64
#define EPS 1e-6f

#define NROWS (BB * TT)          // 32768 flat (b,t) rows

using bf16x8 = __attribute__((ext_vector_type(8))) short;
using s16x4  = __attribute__((ext_vector_type(4))) short;
using f32x4  = __attribute__((ext_vector_type(4))) float;

__device__ __forceinline__ short f2b(float f) {
  __hip_bfloat16 h = __float2bfloat16(f);   // HW RNE (compiler can pack cvt_pk)
  return *reinterpret_cast<short*>(&h);
}
__device__ __forceinline__ float b2f(short s) {
  unsigned u = ((unsigned)(unsigned short)s) << 16;
  return __uint_as_float(u);
}

// async global->LDS 16B copy (dest must be wave-uniform base + lane*16)
__device__ __forceinline__ void gld16(short* lds_dst, const short* gsrc) {
  __builtin_amdgcn_global_load_lds(
      (const __attribute__((address_space(1))) unsigned int*)gsrc,
      (__attribute__((address_space(3))) unsigned int*)lds_dst, 16, 0, 0);
}

// W fp32 [o][c] -> bf16 [o][c]
__global__ __launch_bounds__(256) void conv_w(const float* __restrict__ src,
                                              short* __restrict__ dst)
{
  int i8 = (blockIdx.x * 256 + threadIdx.x) * 8;
  float4 a = *(const float4*)(src + i8);
  float4 b = *(const float4*)(src + i8 + 4);
  bf16x8 h = { f2b(a.x), f2b(a.y), f2b(a.z), f2b(a.w),
               f2b(b.x), f2b(b.y), f2b(b.z), f2b(b.w) };
  *(bf16x8*)(dst + i8) = h;
}

// ---------------------------------------------------------------------------
// transpose+convert: X fp32 [b][c][t] -> Xt bf16 [b][t][c]
// grid (T/64, C/64, B), 256 thr, 64x64 LDS tile (stride 68 shorts).
// ---------------------------------------------------------------------------
__global__ __launch_bounds__(256) void transpose_cvt(const float* __restrict__ X,
                                                     short* __restrict__ Xt)
{
  __shared__ short tile[64 * 68];
  const int t0 = blockIdx.x * 64, c0 = blockIdx.y * 64, b = blockIdx.z;
  const int tid = threadIdx.x;
  // phase A: read rows of X (coalesced float4), write tile[c][t]
  {
    int cl = tid >> 4, t4 = (tid & 15) * 4;
    #pragma unroll
    for (int it = 0; it < 4; ++it) {
      int c = it * 16 + cl;
      float4 v = *(const float4*)(X + ((size_t)b * CC + c0 + c) * TT + t0 + t4);
      s16x4 h = { f2b(v.x), f2b(v.y), f2b(v.z), f2b(v.w) };
      *(s16x4*)&tile[c * 68 + t4] = h;
    }
  }
  __syncthreads();
  // phase B: read tile columns, write rows of Xt (coalesced b128)
  {
    int t = tid >> 2, ci = (tid & 3) * 16;
    short s[16];
    #pragma unroll
    for (int i = 0; i < 16; ++i) s[i] = tile[(ci + i) * 68 + t];
    short* dst = Xt + ((size_t)b * TT + t0 + t) * CC + c0 + ci;
    *(bf16x8*)dst = *(bf16x8*)&s[0];
    *(bf16x8*)(dst + 8) = *(bf16x8*)&s[8];
  }
}

// ---------------------------------------------------------------------------
// GEMM (pure bf16, both K-contig): Y[m][o] = sum_c A[m][c] * W[o][c] + bias[o]
// A = [NROWS][512] bf16, W = [512][512] bf16. 128x128 tile, BK=32, 4 waves.
// m97 structure: global_load_lds(16) both tiles; XCD-chunked block swizzle.
// ---------------------------------------------------------------------------
__global__ __launch_bounds__(256) void gemm_tc(const short* __restrict__ A,
                                               const short* __restrict__ W,
                                               const float* __restrict__ bias,
                                               short* __restrict__ Y)
{
  __shared__ short As[128 * 32];
  __shared__ short Bs[128 * 32];
  const int tid = threadIdx.x;
  // swizzle: 1024 blocks -> each XCD owns a contiguous chunk of m-tiles
  int x = blockIdx.x;
  int wg = (x & 7) * 128 + (x >> 3);
  const int m0 = (wg >> 2) * 128;          // 256 m-tiles
  const int o0 = (wg & 3) * 128;           // 4 o-tiles

  const int wid = tid >> 6, lane = tid & 63;
  const int wr = (wid >> 1) * 64, wc = (wid & 1) * 64;
  const int lr = lane & 15, lk8 = (lane >> 4) * 8;

  f32x4 acc[4][4] = {};

  for (int k0 = 0; k0 < CC; k0 += 32) {
    #pragma unroll
    for (int it = 0; it < 2; ++it) {
      int off = it * 4096 + tid * 16;      // bytes within 8KB tile
      int row = off >> 6, col = (off & 63) >> 1;
      gld16(As + (off >> 1), A + (size_t)(m0 + row) * CC + k0 + col);
      gld16(Bs + (off >> 1), W + (size_t)(o0 + row) * CC + k0 + col);
    }
    __syncthreads();
    bf16x8 af[4], bf[4];
    #pragma unroll
    for (int m = 0; m < 4; ++m) af[m] = *(const bf16x8*)&As[(wr + m * 16 + lr) * 32 + lk8];
    #pragma unroll
    for (int n = 0; n < 4; ++n) bf[n] = *(const bf16x8*)&Bs[(wc + n * 16 + lr) * 32 + lk8];
    #pragma unroll
    for (int m = 0; m < 4; ++m)
      #pragma unroll
      for (int n = 0; n < 4; ++n)
        acc[m][n] = __builtin_amdgcn_mfma_f32_16x16x32_bf16(af[m], bf[n], acc[m][n], 0, 0, 0);
    __syncthreads();
  }

  const int lq4 = (lane >> 4) * 4;
  #pragma unroll
  for (int m = 0; m < 4; ++m)
    #pragma unroll
    for (int r = 0; r < 4; ++r) {
      size_t row = (size_t)(m0 + wr + m * 16 + lq4 + r) * CC;
      #pragma unroll
      for (int n = 0; n < 4; ++n) {
        int o = o0 + wc + n * 16 + lr;
        Y[row + o] = f2b(acc[m][n][r] + bias[o]);
      }
    }
}

// ---------------------------------------------------------------------------
// Row feature kernels on [row][512] bf16, wave per row, in-place.
// MODE: 0=Q (rms->elu+1->per-head softmax->*8^-0.5), 1=K (rms->elu+1),
//       2=V (rms->elu+1->/64)
// ---------------------------------------------------------------------------
template<int MODE>
__global__ __launch_bounds__(256) void feat_row(short* __restrict__ buf,
                                                const float* __restrict__ g)
{
  const int row = blockIdx.x * 4 + (threadIdx.x >> 6);
  const int lane = threadIdx.x & 63;
  short* p = buf + (size_t)row * CC + lane * 8;
  bf16x8 v = *(const bf16x8*)p;
  float x[8], ss = 0.f;
  #pragma unroll
  for (int j = 0; j < 8; ++j) { x[j] = b2f(v[j]); ss += x[j] * x[j]; }
  #pragma unroll
  for (int off = 32; off; off >>= 1) ss += __shfl_xor(ss, off);
  float rn = rsqrtf(ss * (1.0f / CC) + EPS);
  float4 g0 = *(const float4*)(g + lane * 8);
  float4 g1 = *(const float4*)(g + lane * 8 + 4);
  float gv[8] = { g0.x, g0.y, g0.z, g0.w, g1.x, g1.y, g1.z, g1.w };
  float f[8];
  #pragma unroll
  for (int j = 0; j < 8; ++j) {
    float t = x[j] * rn * gv[j];
    f[j] = t > 0.f ? t + 1.f : __expf(t);
  }
  bf16x8 o;
  if constexpr (MODE == 1) {
    #pragma unroll
    for (int j = 0; j < 8; ++j) o[j] = f2b(f[j]);
  } else if constexpr (MODE == 2) {
    #pragma unroll
    for (int j = 0; j < 8; ++j) o[j] = f2b(f[j] * (1.0f / DH));
  } else {  // Q: softmax over head (64 c = 8 lanes), no max-sub (f <= ~24)
    float ls = 0.f;
    #pragma unroll
    for (int j = 0; j < 8; ++j) { f[j] = __expf(f[j]); ls += f[j]; }
    ls += __shfl_xor(ls, 1); ls += __shfl_xor(ls, 2); ls += __shfl_xor(ls, 4);
    float sc = 0.35355339059327373f / ls;     // 8^-0.5 / sum
    #pragma unroll
    for (int j = 0; j < 8; ++j) o[j] = f2b(f[j] * sc);
  }
  *(bf16x8*)p = o;
}

// ---------------------------------------------------------------------------
// k time-softmax (no max-sub: values <= ~24, exp fits fp32; mask -> 0)
// ---------------------------------------------------------------------------
__global__ __launch_bounds__(256) void ksm_sum(const short* __restrict__ kf,
                                               const unsigned char* __restrict__ mask,
                                               float* __restrict__ S)
{
  const int b = blockIdx.y, t0 = blockIdx.x * 64;
  const int c2 = threadIdx.x * 2;
  const unsigned char* mk = mask + (size_t)b * TT + t0;
  float s0 = 0.f, s1 = 0.f;
  for (int t = 0; t < 64; ++t) {
    if (mk[t]) continue;
    unsigned u = *(const unsigned*)&kf[((size_t)b * TT + t0 + t) * CC + c2];
    s0 += __expf(__uint_as_float(u << 16));
    s1 += __expf(__uint_as_float(u & 0xffff0000u));
  }
  atomicAdd(&S[b * CC + c2], s0);
  atomicAdd(&S[b * CC + c2 + 1], s1);
}

__global__ __launch_bounds__(256) void ksm_apply(short* __restrict__ kf,
                                                 const unsigned char* __restrict__ mask,
                                                 const float* __restrict__ S)
{
  const int b = blockIdx.y, t0 = blockIdx.x * 64;
  const int c2 = threadIdx.x * 2;
  const unsigned char* mk = mask + (size_t)b * TT + t0;
  const float i0 = 1.f / S[b * CC + c2];
  const float i1 = 1.f / S[b * CC + c2 + 1];
  for (int t = 0; t < 64; ++t) {
    unsigned* p = (unsigned*)&kf[((size_t)b * TT + t0 + t) * CC + c2];
    if (mk[t]) { *p = 0u; continue; }
    unsigned u = *p;
    float y0 = __expf(__uint_as_float(u << 16)) * i0;
    float y1 = __expf(__uint_as_float(u & 0xffff0000u)) * i1;
    *p = ((unsigned)(unsigned short)f2b(y0)) | (((unsigned)(unsigned short)f2b(y1)) << 16);
  }
}

// ---------------------------------------------------------------------------
// ctx partials from t-major kf/vf: P[tc][bh][q][v] = sum_t kf[t][q]*vf[t][v]
// grid (8 t-chunks of 512, 64 bh), 256 thr. LDS [64t][64c] tiles, gload_lds.
// ---------------------------------------------------------------------------
__global__ __launch_bounds__(256) void ctx_t(const short* __restrict__ kf,
                                             const short* __restrict__ vf,
                                             float* __restrict__ P)
{
  __shared__ short Ks[64 * 64];
  __shared__ short Vs[64 * 64];
  const int tc = blockIdx.x, bh = blockIdx.y;
  const int b = bh >> 3, h = bh & 7;
  const int tid = threadIdx.x, wid = tid >> 6, lane = tid & 63;
  const int lr = lane & 15, lg = lane >> 4;
  f32x4 acc[4] = {};

  for (int ts = 0; ts < 8; ++ts) {
    #pragma unroll
    for (int i = 0; i < 2; ++i) {
      int n = i * 256 + tid;               // 512 chunks of 16B
      int t = n >> 3, ch = (n & 7) * 8;
      size_t src = ((size_t)b * TT + tc * 512 + ts * 64 + t) * CC + h * DH + ch;
      gld16(Ks + n * 8, kf + src);
      gld16(Vs + n * 8, vf + src);
    }
    __syncthreads();
    #pragma unroll
    for (int kk = 0; kk < 64; kk += 32) {
      short a[8];
      #pragma unroll
      for (int j = 0; j < 8; ++j)
        a[j] = Ks[(kk + lg * 8 + j) * 64 + wid * 16 + lr];
      bf16x8 af = *(const bf16x8*)&a[0];
      #pragma unroll
      for (int n = 0; n < 4; ++n) {
        short bv[8];
        #pragma unroll
        for (int j = 0; j < 8; ++j)
          bv[j] = Vs[(kk + lg * 8 + j) * 64 + n * 16 + lr];
        acc[n] = __builtin_amdgcn_mfma_f32_16x16x32_bf16(af, *(const bf16x8*)&bv[0],
                                                         acc[n], 0, 0, 0);
      }
    }
    __syncthreads();
  }
  float* pp = P + ((size_t)tc * 64 + bh) * (DH * DH);
  const int lq4 = lg * 4;
  #pragma unroll
  for (int n = 0; n < 4; ++n)
    #pragma unroll
    for (int r = 0; r < 4; ++r)
      pp[(wid * 16 + lq4 + r) * DH + n * 16 + lr] = acc[n][r];
}

// reduce chunk partials, emit TRANSPOSED bf16 ctx: CT[bh][v][q]
__global__ __launch_bounds__(256) void ctx_reduce(const float* __restrict__ P, short* __restrict__ CT)
{
  int i = blockIdx.x * 256 + threadIdx.x;    // (bh, q, v), v fastest
  float s = 0.f;
  #pragma unroll
  for (int c = 0; c < 8; ++c) s += P[(size_t)c * 64 * DH * DH + i];
  int bh = i >> 12, rem = i & 4095, q = rem >> 6, v = rem & 63;
  CT[((size_t)bh << 12) + v * 64 + q] = f2b(s);
}

// ---------------------------------------------------------------------------
// attn: ao[row][h*64+v] = sum_q qf[row][h*64+q] * CT[bh][v][q]
// ---------------------------------------------------------------------------
__global__ __launch_bounds__(256) void attn_t(const short* __restrict__ qf,
                                              const short* __restrict__ CT,
                                              short* __restrict__ ao)
{
  __shared__ short As[128 * 72];
  __shared__ short Cs[64 * 72];
  const int m0 = blockIdx.x * 128, h = blockIdx.y;
  const int tid = threadIdx.x, wid = tid >> 6, lane = tid & 63;
  const int lr = lane & 15, lk8 = (lane >> 4) * 8;

  #pragma unroll
  for (int i = 0; i < 4; ++i) {
    int n = i * 256 + tid;                 // 1024 chunks
    int r = n >> 3, ch = (n & 7) * 8;
    *(bf16x8*)&As[r * 72 + ch] =
        *(const bf16x8*)(qf + (size_t)(m0 + r) * CC + h * DH + ch);
  }
  {
    const int bh0 = (m0 / TT) * 8 + h;     // batch of this m-tile (tiles don't cross b)
    #pragma unroll
    for (int i = 0; i < 2; ++i) {
      int n = i * 256 + tid;               // 512 chunks
      int v = n >> 3, ch = (n & 7) * 8;
      *(bf16x8*)&Cs[v * 72 + ch] = *(const bf16x8*)(CT + ((size_t)bh0 << 12) + v * 64 + ch);
    }
  }
  __syncthreads();

  const int wr = wid * 32;
  f32x4 acc[2][4] = {};
  #pragma unroll
  for (int kk = 0; kk < 64; kk += 32) {
    bf16x8 af[2], cf[4];
    #pragma unroll
    for (int m = 0; m < 2; ++m) af[m] = *(const bf16x8*)&As[(wr + m * 16 + lr) * 72 + kk + lk8];
    #pragma unroll
    for (int n = 0; n < 4; ++n) cf[n] = *(const bf16x8*)&Cs[(n * 16 + lr) * 72 + kk + lk8];
    #pragma unroll
    for (int m = 0; m < 2; ++m)
      #pragma unroll
      for (int n = 0; n < 4; ++n)
        acc[m][n] = __builtin_amdgcn_mfma_f32_16x16x32_bf16(af[m], cf[n], acc[m][n], 0, 0, 0);
  }
  const int lq4 = (lane >> 4) * 4;
  #pragma unroll
  for (int m = 0; m < 2; ++m)
    #pragma unroll
    for (int r = 0; r < 4; ++r) {
      size_t row = (size_t)(m0 + wr + m * 16 + lq4 + r) * CC + h * DH;
      #pragma unroll
      for (int n = 0; n < 4; ++n)
        ao[row + n * 16 + lr] = f2b(acc[m][n][r]);
    }
}

// ---------------------------------------------------------------------------
// final: rms over (pj + qt) rows; then tiled transpose-write to d_out [c][t]
// ---------------------------------------------------------------------------
__global__ __launch_bounds__(256) void final_a(const short* __restrict__ pj,
                                               const short* __restrict__ qt,
                                               float* __restrict__ rms)
{
  const int row = blockIdx.x * 4 + (threadIdx.x >> 6);
  const int lane = threadIdx.x & 63;
  bf16x8 a = *(const bf16x8*)(pj + (size_t)row * CC + lane * 8);
  bf16x8 b = *(const bf16x8*)(qt + (size_t)row * CC + lane * 8);
  float ss = 0.f;
  #pragma unroll
  for (int j = 0; j < 8; ++j) { float z = b2f(a[j]) + b2f(b[j]); ss += z * z; }
  #pragma unroll
  for (int off = 32; off; off >>= 1) ss += __shfl_xor(ss, off);
  if (lane == 0) rms[row] = rsqrtf(ss * (1.0f / CC) + EPS);
}

// 64t x 64c tile: coalesced bf16 row reads -> LDS fp32 [c][t] -> coalesced
// float4 writes along t. Kills the 3x write amplification of scattered stores.
__global__ __launch_bounds__(256) void final_b(const short* __restrict__ pj,
                                               const short* __restrict__ qt,
                                               const float* __restrict__ rms,
                                               const float* __restrict__ g,
                                               float* __restrict__ out)
{
  __shared__ float tile[64 * 65];
  const int t0 = blockIdx.x * 64, c0 = blockIdx.y * 64, b = blockIdx.z;
  const int tid = threadIdx.x;

  // load/compute: thread = (t = tid>>2, chunk = tid&3 of 16 c)
  {
    const int t = tid >> 2, ch = (tid & 3) * 16;
    const size_t row = ((size_t)b * TT + t0 + t) * CC + c0 + ch;
    bf16x8 a0 = *(const bf16x8*)(pj + row);
    bf16x8 a1 = *(const bf16x8*)(pj + row + 8);
    bf16x8 q0 = *(const bf16x8*)(qt + row);
    bf16x8 q1 = *(const bf16x8*)(qt + row + 8);
    const float r = rms[b * TT + t0 + t];
    #pragma unroll
    for (int j = 0; j < 8; ++j) {
      tile[(ch + j) * 65 + t]     = (b2f(a0[j]) + b2f(q0[j])) * r * g[c0 + ch + j];
      tile[(ch + 8 + j) * 65 + t] = (b2f(a1[j]) + b2f(q1[j])) * r * g[c0 + ch + 8 + j];
    }
  }
  __syncthreads();
  // store: thread = (c = tid>>2, 16 t as 4x float4), contiguous along t
  {
    const int c = tid >> 2, tc = (tid & 3) * 16;
    float* dst = out + ((size_t)b * CC + c0 + c) * TT + t0 + tc;
    #pragma unroll
    for (int i = 0; i < 4; ++i) {
      float4 v = { tile[c * 65 + tc + i * 4],     tile[c * 65 + tc + i * 4 + 1],
                   tile[c * 65 + tc + i * 4 + 2], tile[c * 65 + tc + i * 4 + 3] };
      *(float4*)(dst + i * 4) = v;
    }
  }
}

// ---------------------------------------------------------------------------
extern "C" void kernel_launch(void* const* d_in, const int* in_sizes, int n_in,
                              void* d_out, int out_size, void* d_ws, size_t ws_size,
                              hipStream_t stream) {
  (void)in_sizes; (void)n_in; (void)out_size; (void)ws_size;
  const float* queries = (const float*)d_in[0];
  const float* keys    = (const float*)d_in[1];
  const float* values  = (const float*)d_in[2];
  const unsigned char* mask = (const unsigned char*)d_in[3];
  const float* Wq = (const float*)d_in[4];
  const float* bq = (const float*)d_in[5];
  const float* gq = (const float*)d_in[6];
  const float* Wk = (const float*)d_in[7];
  const float* bk = (const float*)d_in[8];
  const float* gk = (const float*)d_in[9];
  const float* Wv = (const float*)d_in[10];
  const float* bv = (const float*)d_in[11];
  const float* gv = (const float*)d_in[12];
  const float* Wp = (const float*)d_in[13];
  const float* bp = (const float*)d_in[14];
  const float* g_out = (const float*)d_in[15];

  const size_t NCT = (size_t)NROWS * CC;       // 16,777,216 elements
  short* qt = (short*)d_ws;                    // bf16 [row][c] transposed inputs
  short* kt = qt + NCT;
  short* vt = kt + NCT;
  short* qf = vt + NCT;                        // gemm outputs / features (in-place)
  short* kf = qf + NCT;
  short* vf = kf + NCT;
  short* ao = kt;                              // reuse (kt dead after its gemm)
  short* pj = vt;                              // reuse (vt dead after its gemm)
  float* ctxP = (float*)(vf + NCT);            // 8 x 64 x 4096 fp32
  short* CT  = (short*)(ctxP + (size_t)8 * 64 * DH * DH);   // [bh][v][q] bf16
  short* wqb = CT + (size_t)64 * DH * DH;
  short* wkb = wqb + (size_t)CC * CC;
  short* wvb = wkb + (size_t)CC * CC;
  short* wpb = wvb + (size_t)CC * CC;
  float* S   = (float*)(wpb + (size_t)CC * CC);   // [B][C] softmax sums
  float* rms = S + (size_t)BB * CC;               // [row]

  hipMemsetAsync(S, 0, (size_t)BB * CC * sizeof(float), stream);

  conv_w<<<dim3(CC * CC / 2048), 256, 0, stream>>>(Wq, wqb);
  conv_w<<<dim3(CC * CC / 2048), 256, 0, stream>>>(Wk, wkb);
  conv_w<<<dim3(CC * CC / 2048), 256, 0, stream>>>(Wv, wvb);
  conv_w<<<dim3(CC * CC / 2048), 256, 0, stream>>>(Wp, wpb);

  dim3 gT(TT / 64, CC / 64, BB);
  transpose_cvt<<<gT, 256, 0, stream>>>(queries, qt);
  transpose_cvt<<<gT, 256, 0, stream>>>(keys,    kt);
  transpose_cvt<<<gT, 256, 0, stream>>>(values,  vt);

  dim3 gG(1024);
  gemm_tc<<<gG, 256, 0, stream>>>(qt, wqb, bq, qf);
  gemm_tc<<<gG, 256, 0, stream>>>(kt, wkb, bk, kf);
  gemm_tc<<<gG, 256, 0, stream>>>(vt, wvb, bv, vf);

  feat_row<0><<<dim3(NROWS / 4), 256, 0, stream>>>(qf, gq);
  feat_row<1><<<dim3(NROWS / 4), 256, 0, stream>>>(kf, gk);
  feat_row<2><<<dim3(NROWS / 4), 256, 0, stream>>>(vf, gv);

  dim3 gS(TT / 64, BB);
  ksm_sum<<<gS, 256, 0, stream>>>(kf, mask, S);
  ksm_apply<<<gS, 256, 0, stream>>>(kf, mask, S);

  ctx_t<<<dim3(8, BB * HH), 256, 0, stream>>>(kf, vf, ctxP);
  ctx_reduce<<<dim3(64 * DH * DH / 256), 256, 0, stream>>>(ctxP, CT);

  attn_t<<<dim3(NROWS / 128, HH), 256, 0, stream>>>(qf, CT, ao);

  gemm_tc<<<gG, 256, 0, stream>>>(ao, wpb, bp, pj);

  final_a<<<dim3(NROWS / 4), 256, 0, stream>>>(pj, qt, rms);
  final_b<<<dim3(TT / 64, CC / 64, BB), 256, 0, stream>>>(pj, qt, rms, g_out, (float*)d_out);
}

// Round 8
// 339.866 us; speedup vs baseline: 1.3937x; 1.0668x over previous
//
#include <hip/hip_runtime.h>
#include <hip/hip_bf16.h>

// Problem constants (fixed by the reference)
#define BB 8
#define CC 512
#define TT 4096
#define HH 8
#define DH 64
#define EPS 1e-6f

#define NROWS (BB * TT)          // 32768 flat (b,t) rows

using bf16x8 = __attribute__((ext_vector_type(8))) short;
using s16x4  = __attribute__((ext_vector_type(4))) short;
using f32x4  = __attribute__((ext_vector_type(4))) float;

__device__ __forceinline__ short f2b(float f) {
  __hip_bfloat16 h = __float2bfloat16(f);
  return *reinterpret_cast<short*>(&h);
}
__device__ __forceinline__ float b2f(short s) {
  unsigned u = ((unsigned)(unsigned short)s) << 16;
  return __uint_as_float(u);
}

// async global->LDS 16B copy (dest must be wave-uniform base + lane*16)
__device__ __forceinline__ void gld16(short* lds_dst, const short* gsrc) {
  __builtin_amdgcn_global_load_lds(
      (const __attribute__((address_space(1))) unsigned int*)gsrc,
      (__attribute__((address_space(3))) unsigned int*)lds_dst, 16, 0, 0);
}

// 4 weights fp32 [o][c] -> bf16 [o][c], one launch
__global__ __launch_bounds__(256) void conv_w4(const float* __restrict__ s0, const float* __restrict__ s1,
                                               const float* __restrict__ s2, const float* __restrict__ s3,
                                               short* __restrict__ d0, short* __restrict__ d1,
                                               short* __restrict__ d2, short* __restrict__ d3)
{
  const float* src; short* dst;
  switch (blockIdx.y) {
    case 0: src = s0; dst = d0; break;
    case 1: src = s1; dst = d1; break;
    case 2: src = s2; dst = d2; break;
    default: src = s3; dst = d3; break;
  }
  int i8 = (blockIdx.x * 256 + threadIdx.x) * 8;
  float4 a = *(const float4*)(src + i8);
  float4 b = *(const float4*)(src + i8 + 4);
  bf16x8 h = { f2b(a.x), f2b(a.y), f2b(a.z), f2b(a.w),
               f2b(b.x), f2b(b.y), f2b(b.z), f2b(b.w) };
  *(bf16x8*)(dst + i8) = h;
}

// ---------------------------------------------------------------------------
// transpose+convert: X fp32 [b][c][t] -> Xt bf16 [b][t][c], all 3 tensors in
// one launch. grid (T/64, C/64, 3*B).
// ---------------------------------------------------------------------------
__global__ __launch_bounds__(256) void transpose_cvt3(const float* __restrict__ X0,
                                                      const float* __restrict__ X1,
                                                      const float* __restrict__ X2,
                                                      short* __restrict__ Y0,
                                                      short* __restrict__ Y1,
                                                      short* __restrict__ Y2)
{
  __shared__ short tile[64 * 68];
  const int t0 = blockIdx.x * 64, c0 = blockIdx.y * 64;
  const int b = blockIdx.z & 7, which = blockIdx.z >> 3;
  const float* X = which == 0 ? X0 : (which == 1 ? X1 : X2);
  short* Xt = which == 0 ? Y0 : (which == 1 ? Y1 : Y2);
  const int tid = threadIdx.x;
  {
    int cl = tid >> 4, t4 = (tid & 15) * 4;
    #pragma unroll
    for (int it = 0; it < 4; ++it) {
      int c = it * 16 + cl;
      float4 v = *(const float4*)(X + ((size_t)b * CC + c0 + c) * TT + t0 + t4);
      s16x4 h = { f2b(v.x), f2b(v.y), f2b(v.z), f2b(v.w) };
      *(s16x4*)&tile[c * 68 + t4] = h;
    }
  }
  __syncthreads();
  {
    int t = tid >> 2, ci = (tid & 3) * 16;
    short s[16];
    #pragma unroll
    for (int i = 0; i < 16; ++i) s[i] = tile[(ci + i) * 68 + t];
    short* dst = Xt + ((size_t)b * TT + t0 + t) * CC + c0 + ci;
    *(bf16x8*)dst = *(bf16x8*)&s[0];
    *(bf16x8*)(dst + 8) = *(bf16x8*)&s[8];
  }
}

// ---------------------------------------------------------------------------
// GEMM: Y[m][o] = sum_c A[m][c] * W[o][c] + bias[o]. 128x128 tile, BK=32,
// double-buffered LDS (2-phase: issue next-tile gld16 BEFORE compute, one
// barrier/step). Bank-conflict-free via both-sides XOR swizzle:
// LDS dest linear; global source chunk ^= (row>>1)&3; read chunk ^= (lr>>1)&3.
// ---------------------------------------------------------------------------
__global__ __launch_bounds__(256) void gemm_tc(const short* __restrict__ A,
                                               const short* __restrict__ W,
                                               const float* __restrict__ bias,
                                               short* __restrict__ Y)
{
  __shared__ short As[2][4096];
  __shared__ short Bs[2][4096];
  const int tid = threadIdx.x;
  int x = blockIdx.x;
  int wg = (x & 7) * 128 + (x >> 3);       // XCD-chunked
  const int m0 = (wg >> 2) * 128;          // 256 m-tiles
  const int o0 = (wg & 3) * 128;           // 4 o-tiles

  const int wid = tid >> 6, lane = tid & 63;
  const int wr = (wid >> 1) * 64, wc = (wid & 1) * 64;
  const int lr = lane & 15, g = lane >> 4;
  const int swz8 = (g ^ ((lr >> 1) & 3)) * 8;           // read-side swizzle

  // staging geometry: thread covers off = it*4096 + tid*16 bytes
  const int srow0 = tid >> 2;                            // + it*64
  const int scol  = ((tid & 3) ^ ((tid >> 3) & 3)) * 8;  // source-side swizzle

  f32x4 acc[4][4] = {};

  #pragma unroll
  for (int it = 0; it < 2; ++it) {
    int row = it * 64 + srow0;
    gld16(&As[0][it * 2048 + tid * 8], A + (size_t)(m0 + row) * CC + scol);
    gld16(&Bs[0][it * 2048 + tid * 8], W + (size_t)(o0 + row) * CC + scol);
  }
  __syncthreads();

  for (int step = 0; step < 16; ++step) {
    const int cur = step & 1;
    if (step < 15) {
      const int k0 = (step + 1) * 32;
      #pragma unroll
      for (int it = 0; it < 2; ++it) {
        int row = it * 64 + srow0;
        gld16(&As[cur ^ 1][it * 2048 + tid * 8], A + (size_t)(m0 + row) * CC + k0 + scol);
        gld16(&Bs[cur ^ 1][it * 2048 + tid * 8], W + (size_t)(o0 + row) * CC + k0 + scol);
      }
    }
    bf16x8 af[4], bf[4];
    #pragma unroll
    for (int m = 0; m < 4; ++m) af[m] = *(const bf16x8*)&As[cur][(wr + m * 16 + lr) * 32 + swz8];
    #pragma unroll
    for (int n = 0; n < 4; ++n) bf[n] = *(const bf16x8*)&Bs[cur][(wc + n * 16 + lr) * 32 + swz8];
    #pragma unroll
    for (int m = 0; m < 4; ++m)
      #pragma unroll
      for (int n = 0; n < 4; ++n)
        acc[m][n] = __builtin_amdgcn_mfma_f32_16x16x32_bf16(af[m], bf[n], acc[m][n], 0, 0, 0);
    __syncthreads();   // compiler drains vmcnt(0) (next buf ready) + lgkmcnt
  }

  const int lq4 = (lane >> 4) * 4;
  #pragma unroll
  for (int m = 0; m < 4; ++m)
    #pragma unroll
    for (int r = 0; r < 4; ++r) {
      size_t row = (size_t)(m0 + wr + m * 16 + lq4 + r) * CC;
      #pragma unroll
      for (int n = 0; n < 4; ++n) {
        int o = o0 + wc + n * 16 + lr;
        Y[row + o] = f2b(acc[m][n][r] + bias[o]);
      }
    }
}

// ---------------------------------------------------------------------------
// Row feature kernels on [row][512] bf16, wave per row, in-place.
// MODE: 0=Q (rms->elu+1->per-head softmax->*8^-0.5)
//       1=K (rms->elu+1->EXP, masked rows -> 0)   [normalization deferred]
//       2=V (rms->elu+1->/64)
// ---------------------------------------------------------------------------
template<int MODE>
__global__ __launch_bounds__(256) void feat_row(short* __restrict__ buf,
                                                const float* __restrict__ g,
                                                const unsigned char* __restrict__ mask)
{
  const int row = blockIdx.x * 4 + (threadIdx.x >> 6);
  const int lane = threadIdx.x & 63;
  short* p = buf + (size_t)row * CC + lane * 8;
  if constexpr (MODE == 1) {
    if (mask[row]) {                      // whole (b,t) row masked -> exp = 0
      bf16x8 z = { 0,0,0,0,0,0,0,0 };
      *(bf16x8*)p = z;
      return;
    }
  }
  bf16x8 v = *(const bf16x8*)p;
  float x[8], ss = 0.f;
  #pragma unroll
  for (int j = 0; j < 8; ++j) { x[j] = b2f(v[j]); ss += x[j] * x[j]; }
  #pragma unroll
  for (int off = 32; off; off >>= 1) ss += __shfl_xor(ss, off);
  float rn = rsqrtf(ss * (1.0f / CC) + EPS);
  float4 g0 = *(const float4*)(g + lane * 8);
  float4 g1 = *(const float4*)(g + lane * 8 + 4);
  float gv[8] = { g0.x, g0.y, g0.z, g0.w, g1.x, g1.y, g1.z, g1.w };
  float f[8];
  #pragma unroll
  for (int j = 0; j < 8; ++j) {
    float t = x[j] * rn * gv[j];
    f[j] = t > 0.f ? t + 1.f : __expf(t);
  }
  bf16x8 o;
  if constexpr (MODE == 1) {
    #pragma unroll
    for (int j = 0; j < 8; ++j) o[j] = f2b(__expf(f[j]));   // unnormalized exp
  } else if constexpr (MODE == 2) {
    #pragma unroll
    for (int j = 0; j < 8; ++j) o[j] = f2b(f[j] * (1.0f / DH));
  } else {  // Q: softmax over head (64 c = 8 lanes), no max-sub (f <= ~24)
    float ls = 0.f;
    #pragma unroll
    for (int j = 0; j < 8; ++j) { f[j] = __expf(f[j]); ls += f[j]; }
    ls += __shfl_xor(ls, 1); ls += __shfl_xor(ls, 2); ls += __shfl_xor(ls, 4);
    float sc = 0.35355339059327373f / ls;     // 8^-0.5 / sum
    #pragma unroll
    for (int j = 0; j < 8; ++j) o[j] = f2b(f[j] * sc);
  }
  *(bf16x8*)p = o;
}

// column-sum of kf_exp over t: S[b][c] = sum_t kfe[b][t][c]
// grid (32 t-chunks of 128, B); coalesced 1KB rows per t-iter.
__global__ __launch_bounds__(256) void ksm_sum(const short* __restrict__ kfe,
                                               float* __restrict__ S)
{
  const int b = blockIdx.y, tch = blockIdx.x;
  const int c2 = threadIdx.x * 2;
  float s0 = 0.f, s1 = 0.f;
  for (int t = 0; t < 128; ++t) {
    unsigned u = *(const unsigned*)&kfe[((size_t)b * TT + tch * 128 + t) * CC + c2];
    s0 += __uint_as_float(u << 16);
    s1 += __uint_as_float(u & 0xffff0000u);
  }
  atomicAdd(&S[b * CC + c2], s0);
  atomicAdd(&S[b * CC + c2 + 1], s1);
}

// ---------------------------------------------------------------------------
// ctx partials from t-major kfe/vf: P[tc][bh][q][v] = sum_t kfe[t][q]*vf[t][v]
// ---------------------------------------------------------------------------
__global__ __launch_bounds__(256) void ctx_t(const short* __restrict__ kf,
                                             const short* __restrict__ vf,
                                             float* __restrict__ P)
{
  __shared__ short Ks[64 * 64];
  __shared__ short Vs[64 * 64];
  const int tc = blockIdx.x, bh = blockIdx.y;
  const int b = bh >> 3, h = bh & 7;
  const int tid = threadIdx.x, wid = tid >> 6, lane = tid & 63;
  const int lr = lane & 15, lg = lane >> 4;
  f32x4 acc[4] = {};

  for (int ts = 0; ts < 8; ++ts) {
    #pragma unroll
    for (int i = 0; i < 2; ++i) {
      int n = i * 256 + tid;
      int t = n >> 3, ch = (n & 7) * 8;
      size_t src = ((size_t)b * TT + tc * 512 + ts * 64 + t) * CC + h * DH + ch;
      gld16(Ks + n * 8, kf + src);
      gld16(Vs + n * 8, vf + src);
    }
    __syncthreads();
    #pragma unroll
    for (int kk = 0; kk < 64; kk += 32) {
      short a[8];
      #pragma unroll
      for (int j = 0; j < 8; ++j)
        a[j] = Ks[(kk + lg * 8 + j) * 64 + wid * 16 + lr];
      bf16x8 af = *(const bf16x8*)&a[0];
      #pragma unroll
      for (int n = 0; n < 4; ++n) {
        short bv[8];
        #pragma unroll
        for (int j = 0; j < 8; ++j)
          bv[j] = Vs[(kk + lg * 8 + j) * 64 + n * 16 + lr];
        acc[n] = __builtin_amdgcn_mfma_f32_16x16x32_bf16(af, *(const bf16x8*)&bv[0],
                                                         acc[n], 0, 0, 0);
      }
    }
    __syncthreads();
  }
  float* pp = P + ((size_t)tc * 64 + bh) * (DH * DH);
  const int lq4 = lg * 4;
  #pragma unroll
  for (int n = 0; n < 4; ++n)
    #pragma unroll
    for (int r = 0; r < 4; ++r)
      pp[(wid * 16 + lq4 + r) * DH + n * 16 + lr] = acc[n][r];
}

// reduce chunk partials, apply 1/S (deferred k-softmax norm), emit CT[bh][v][q]
__global__ __launch_bounds__(256) void ctx_reduce(const float* __restrict__ P,
                                                  const float* __restrict__ S,
                                                  short* __restrict__ CT)
{
  int i = blockIdx.x * 256 + threadIdx.x;    // (bh, q, v), v fastest
  float s = 0.f;
  #pragma unroll
  for (int c = 0; c < 8; ++c) s += P[(size_t)c * 64 * DH * DH + i];
  int bh = i >> 12, rem = i & 4095, q = rem >> 6, v = rem & 63;
  int b = bh >> 3, h = bh & 7;
  float inv = 1.f / S[b * CC + h * DH + q];
  CT[((size_t)bh << 12) + v * 64 + q] = f2b(s * inv);
}

// ---------------------------------------------------------------------------
// attn: ao[row][h*64+v] = sum_q qf[row][h*64+q] * CT[bh][v][q]
// ---------------------------------------------------------------------------
__global__ __launch_bounds__(256) void attn_t(const short* __restrict__ qf,
                                              const short* __restrict__ CT,
                                              short* __restrict__ ao)
{
  __shared__ short As[128 * 72];
  __shared__ short Cs[64 * 72];
  const int m0 = blockIdx.x * 128, h = blockIdx.y;
  const int tid = threadIdx.x, wid = tid >> 6, lane = tid & 63;
  const int lr = lane & 15, lk8 = (lane >> 4) * 8;

  #pragma unroll
  for (int i = 0; i < 4; ++i) {
    int n = i * 256 + tid;
    int r = n >> 3, ch = (n & 7) * 8;
    *(bf16x8*)&As[r * 72 + ch] =
        *(const bf16x8*)(qf + (size_t)(m0 + r) * CC + h * DH + ch);
  }
  {
    const int bh0 = (m0 / TT) * 8 + h;
    #pragma unroll
    for (int i = 0; i < 2; ++i) {
      int n = i * 256 + tid;
      int v = n >> 3, ch = (n & 7) * 8;
      *(bf16x8*)&Cs[v * 72 + ch] = *(const bf16x8*)(CT + ((size_t)bh0 << 12) + v * 64 + ch);
    }
  }
  __syncthreads();

  const int wr = wid * 32;
  f32x4 acc[2][4] = {};
  #pragma unroll
  for (int kk = 0; kk < 64; kk += 32) {
    bf16x8 af[2], cf[4];
    #pragma unroll
    for (int m = 0; m < 2; ++m) af[m] = *(const bf16x8*)&As[(wr + m * 16 + lr) * 72 + kk + lk8];
    #pragma unroll
    for (int n = 0; n < 4; ++n) cf[n] = *(const bf16x8*)&Cs[(n * 16 + lr) * 72 + kk + lk8];
    #pragma unroll
    for (int m = 0; m < 2; ++m)
      #pragma unroll
      for (int n = 0; n < 4; ++n)
        acc[m][n] = __builtin_amdgcn_mfma_f32_16x16x32_bf16(af[m], cf[n], acc[m][n], 0, 0, 0);
  }
  const int lq4 = (lane >> 4) * 4;
  #pragma unroll
  for (int m = 0; m < 2; ++m)
    #pragma unroll
    for (int r = 0; r < 4; ++r) {
      size_t row = (size_t)(m0 + wr + m * 16 + lq4 + r) * CC + h * DH;
      #pragma unroll
      for (int n = 0; n < 4; ++n)
        ao[row + n * 16 + lr] = f2b(acc[m][n][r]);
    }
}

// ---------------------------------------------------------------------------
// fused final: per (64t, b) block: pass1 rms over full 512-c rows (pj+qt),
// pass2 transform + LDS transpose + coalesced float4 stores to [c][t].
// ---------------------------------------------------------------------------
__global__ __launch_bounds__(256) void final_fused(const short* __restrict__ pj,
                                                   const short* __restrict__ qt,
                                                   const float* __restrict__ g,
                                                   float* __restrict__ out)
{
  __shared__ float tile[64 * 65];
  __shared__ float rmss[64];
  const int t0 = blockIdx.x * 64, b = blockIdx.y;
  const int tid = threadIdx.x;

  // pass 1: rms per row; thread = (t = tid>>2, 128-c range = (tid&3)*128)
  {
    const int t = tid >> 2, cb = (tid & 3) * 128;
    const size_t row = ((size_t)b * TT + t0 + t) * CC + cb;
    float ss = 0.f;
    #pragma unroll
    for (int j = 0; j < 16; ++j) {
      bf16x8 a = *(const bf16x8*)(pj + row + j * 8);
      bf16x8 q = *(const bf16x8*)(qt + row + j * 8);
      #pragma unroll
      for (int e = 0; e < 8; ++e) { float z = b2f(a[e]) + b2f(q[e]); ss += z * z; }
    }
    ss += __shfl_xor(ss, 1);
    ss += __shfl_xor(ss, 2);
    if ((tid & 3) == 0) rmss[t] = rsqrtf(ss * (1.0f / CC) + EPS);
  }
  __syncthreads();

  // pass 2: 8 c-blocks of 64 (reads are L2-hot from pass 1)
  for (int cb8 = 0; cb8 < 8; ++cb8) {
    const int c0 = cb8 * 64;
    {
      const int t = tid >> 2, ch = (tid & 3) * 16;
      const size_t row = ((size_t)b * TT + t0 + t) * CC + c0 + ch;
      bf16x8 a0 = *(const bf16x8*)(pj + row);
      bf16x8 a1 = *(const bf16x8*)(pj + row + 8);
      bf16x8 q0 = *(const bf16x8*)(qt + row);
      bf16x8 q1 = *(const bf16x8*)(qt + row + 8);
      const float r = rmss[t];
      #pragma unroll
      for (int j = 0; j < 8; ++j) {
        tile[(ch + j) * 65 + t]     = (b2f(a0[j]) + b2f(q0[j])) * r * g[c0 + ch + j];
        tile[(ch + 8 + j) * 65 + t] = (b2f(a1[j]) + b2f(q1[j])) * r * g[c0 + ch + 8 + j];
      }
    }
    __syncthreads();
    {
      const int c = tid >> 2, tc = (tid & 3) * 16;
      float* dst = out + ((size_t)b * CC + c0 + c) * TT + t0 + tc;
      #pragma unroll
      for (int i = 0; i < 4; ++i) {
        float4 v = { tile[c * 65 + tc + i * 4],     tile[c * 65 + tc + i * 4 + 1],
                     tile[c * 65 + tc + i * 4 + 2], tile[c * 65 + tc + i * 4 + 3] };
        *(float4*)(dst + i * 4) = v;
      }
    }
    __syncthreads();
  }
}

// ---------------------------------------------------------------------------
extern "C" void kernel_launch(void* const* d_in, const int* in_sizes, int n_in,
                              void* d_out, int out_size, void* d_ws, size_t ws_size,
                              hipStream_t stream) {
  (void)in_sizes; (void)n_in; (void)out_size; (void)ws_size;
  const float* queries = (const float*)d_in[0];
  const float* keys    = (const float*)d_in[1];
  const float* values  = (const float*)d_in[2];
  const unsigned char* mask = (const unsigned char*)d_in[3];
  const float* Wq = (const float*)d_in[4];
  const float* bq = (const float*)d_in[5];
  const float* gq = (const float*)d_in[6];
  const float* Wk = (const float*)d_in[7];
  const float* bk = (const float*)d_in[8];
  const float* gk = (const float*)d_in[9];
  const float* Wv = (const float*)d_in[10];
  const float* bv = (const float*)d_in[11];
  const float* gv = (const float*)d_in[12];
  const float* Wp = (const float*)d_in[13];
  const float* bp = (const float*)d_in[14];
  const float* g_out = (const float*)d_in[15];

  const size_t NCT = (size_t)NROWS * CC;       // 16,777,216 elements
  short* qt = (short*)d_ws;                    // bf16 [row][c] transposed inputs
  short* kt = qt + NCT;
  short* vt = kt + NCT;
  short* qf = vt + NCT;                        // gemm outputs / features (in-place)
  short* kf = qf + NCT;
  short* vf = kf + NCT;
  short* ao = kt;                              // reuse (kt dead after its gemm)
  short* pj = vt;                              // reuse (vt dead after its gemm)
  float* ctxP = (float*)(vf + NCT);            // 8 x 64 x 4096 fp32
  short* CT  = (short*)(ctxP + (size_t)8 * 64 * DH * DH);   // [bh][v][q] bf16
  short* wqb = CT + (size_t)64 * DH * DH;
  short* wkb = wqb + (size_t)CC * CC;
  short* wvb = wkb + (size_t)CC * CC;
  short* wpb = wvb + (size_t)CC * CC;
  float* S   = (float*)(wpb + (size_t)CC * CC);   // [B][C] softmax sums

  hipMemsetAsync(S, 0, (size_t)BB * CC * sizeof(float), stream);

  conv_w4<<<dim3(CC * CC / 2048, 4), 256, 0, stream>>>(Wq, Wk, Wv, Wp, wqb, wkb, wvb, wpb);

  transpose_cvt3<<<dim3(TT / 64, CC / 64, 3 * BB), 256, 0, stream>>>(
      queries, keys, values, qt, kt, vt);

  dim3 gG(1024);
  gemm_tc<<<gG, 256, 0, stream>>>(qt, wqb, bq, qf);
  gemm_tc<<<gG, 256, 0, stream>>>(kt, wkb, bk, kf);
  gemm_tc<<<gG, 256, 0, stream>>>(vt, wvb, bv, vf);

  feat_row<0><<<dim3(NROWS / 4), 256, 0, stream>>>(qf, gq, mask);
  feat_row<1><<<dim3(NROWS / 4), 256, 0, stream>>>(kf, gk, mask);
  feat_row<2><<<dim3(NROWS / 4), 256, 0, stream>>>(vf, gv, mask);

  ksm_sum<<<dim3(32, BB), 256, 0, stream>>>(kf, S);

  ctx_t<<<dim3(8, BB * HH), 256, 0, stream>>>(kf, vf, ctxP);
  ctx_reduce<<<dim3(64 * DH * DH / 256), 256, 0, stream>>>(ctxP, S, CT);

  attn_t<<<dim3(NROWS / 128, HH), 256, 0, stream>>>(qf, CT, ao);

  gemm_tc<<<gG, 256, 0, stream>>>(ao, wpb, bp, pj);

  final_fused<<<dim3(TT / 64, BB), 256, 0, stream>>>(pj, qt, g_out, (float*)d_out);
}

// Round 9
// 319.326 us; speedup vs baseline: 1.4834x; 1.0643x over previous
//
#include <hip/hip_runtime.h>
#include <hip/hip_bf16.h>

// Problem constants (fixed by the reference)
#define BB 8
#define CC 512
#define TT 4096
#define HH 8
#define DH 64
#define EPS 1e-6f

#define NROWS (BB * TT)          // 32768 flat (b,t) rows

using bf16x8 = __attribute__((ext_vector_type(8))) short;
using s16x4  = __attribute__((ext_vector_type(4))) short;
using f32x4  = __attribute__((ext_vector_type(4))) float;

__device__ __forceinline__ short f2b(float f) {
  __hip_bfloat16 h = __float2bfloat16(f);
  return *reinterpret_cast<short*>(&h);
}
__device__ __forceinline__ float b2f(short s) {
  unsigned u = ((unsigned)(unsigned short)s) << 16;
  return __uint_as_float(u);
}

// async global->LDS 16B copy (dest must be wave-uniform base + lane*16)
__device__ __forceinline__ void gld16(short* lds_dst, const short* gsrc) {
  __builtin_amdgcn_global_load_lds(
      (const __attribute__((address_space(1))) unsigned int*)gsrc,
      (__attribute__((address_space(3))) unsigned int*)lds_dst, 16, 0, 0);
}

// 4 weights fp32 [o][c] -> bf16 [o][c], one launch
__global__ __launch_bounds__(256) void conv_w4(const float* __restrict__ s0, const float* __restrict__ s1,
                                               const float* __restrict__ s2, const float* __restrict__ s3,
                                               short* __restrict__ d0, short* __restrict__ d1,
                                               short* __restrict__ d2, short* __restrict__ d3)
{
  const float* src; short* dst;
  switch (blockIdx.y) {
    case 0: src = s0; dst = d0; break;
    case 1: src = s1; dst = d1; break;
    case 2: src = s2; dst = d2; break;
    default: src = s3; dst = d3; break;
  }
  int i8 = (blockIdx.x * 256 + threadIdx.x) * 8;
  float4 a = *(const float4*)(src + i8);
  float4 b = *(const float4*)(src + i8 + 4);
  bf16x8 h = { f2b(a.x), f2b(a.y), f2b(a.z), f2b(a.w),
               f2b(b.x), f2b(b.y), f2b(b.z), f2b(b.w) };
  *(bf16x8*)(dst + i8) = h;
}

// ---------------------------------------------------------------------------
// transpose+convert v2: X fp32 [b][c][t] -> Xt bf16 [b][t][c].
// grid (T/256, C/64, 3*B); per block 4 sub-tiles of 64t x 64c along t,
// double-buffered LDS, next-tile loads issued before the single barrier.
// ---------------------------------------------------------------------------
__global__ __launch_bounds__(256) void transpose_cvt3(const float* __restrict__ X0,
                                                      const float* __restrict__ X1,
                                                      const float* __restrict__ X2,
                                                      short* __restrict__ Y0,
                                                      short* __restrict__ Y1,
                                                      short* __restrict__ Y2)
{
  __shared__ short tile[2][64 * 68];
  const int t0 = blockIdx.x * 256, c0 = blockIdx.y * 64;
  const int b = blockIdx.z & 7, which = blockIdx.z >> 3;
  const float* X = which == 0 ? X0 : (which == 1 ? X1 : X2);
  short* Xt = which == 0 ? Y0 : (which == 1 ? Y1 : Y2);
  const int tid = threadIdx.x;
  const int cl = tid >> 4, t4 = (tid & 15) * 4;     // phase A coords
  const int tb = tid >> 2, ci = (tid & 3) * 16;     // phase B coords

  float4 r[4];
  #pragma unroll
  for (int it = 0; it < 4; ++it)
    r[it] = *(const float4*)(X + ((size_t)b * CC + c0 + it * 16 + cl) * TT + t0 + t4);

  for (int s = 0; s < 4; ++s) {
    const int cur = s & 1;
    #pragma unroll
    for (int it = 0; it < 4; ++it) {
      s16x4 h = { f2b(r[it].x), f2b(r[it].y), f2b(r[it].z), f2b(r[it].w) };
      *(s16x4*)&tile[cur][(it * 16 + cl) * 68 + t4] = h;
    }
    if (s < 3) {
      #pragma unroll
      for (int it = 0; it < 4; ++it)
        r[it] = *(const float4*)(X + ((size_t)b * CC + c0 + it * 16 + cl) * TT
                                 + t0 + (s + 1) * 64 + t4);
    }
    __syncthreads();
    short sreg[16];
    #pragma unroll
    for (int i = 0; i < 16; ++i) sreg[i] = tile[cur][(ci + i) * 68 + tb];
    short* dst = Xt + ((size_t)b * TT + t0 + s * 64 + tb) * CC + c0 + ci;
    *(bf16x8*)dst = *(bf16x8*)&sreg[0];
    *(bf16x8*)(dst + 8) = *(bf16x8*)&sreg[8];
    // single barrier per sub-tile is safe: a thread's LDS reads of buffer
    // (cur^1) completed before its global store (data dep) which precedes
    // the next barrier — so writes to (cur^1) next iteration can't race.
  }
}

// ---------------------------------------------------------------------------
// GEMM body: Y[m][o] = sum_c A[m][c] * W[o][c] + bias[o]. 128x128, BK=32,
// double-buffered LDS, both-sides XOR swizzle, gld16 staging.
// ---------------------------------------------------------------------------
__device__ __forceinline__ void gemm_body(const short* __restrict__ A,
                                          const short* __restrict__ W,
                                          const float* __restrict__ bias,
                                          short* __restrict__ Y,
                                          short* As, short* Bs, int x, int tid)
{
  int wg = (x & 7) * 128 + (x >> 3);       // XCD-chunked
  const int m0 = (wg >> 2) * 128;          // 256 m-tiles
  const int o0 = (wg & 3) * 128;           // 4 o-tiles

  const int wid = tid >> 6, lane = tid & 63;
  const int wr = (wid >> 1) * 64, wc = (wid & 1) * 64;
  const int lr = lane & 15, g = lane >> 4;
  const int swz8 = (g ^ ((lr >> 1) & 3)) * 8;           // read-side swizzle

  const int srow0 = tid >> 2;                            // + it*64
  const int scol  = ((tid & 3) ^ ((tid >> 3) & 3)) * 8;  // source-side swizzle

  f32x4 acc[4][4] = {};

  #pragma unroll
  for (int it = 0; it < 2; ++it) {
    int row = it * 64 + srow0;
    gld16(&As[it * 2048 + tid * 8], A + (size_t)(m0 + row) * CC + scol);
    gld16(&Bs[it * 2048 + tid * 8], W + (size_t)(o0 + row) * CC + scol);
  }
  __syncthreads();

  for (int step = 0; step < 16; ++step) {
    const int cur = step & 1;
    if (step < 15) {
      const int k0 = (step + 1) * 32;
      #pragma unroll
      for (int it = 0; it < 2; ++it) {
        int row = it * 64 + srow0;
        gld16(&As[(cur ^ 1) * 4096 + it * 2048 + tid * 8], A + (size_t)(m0 + row) * CC + k0 + scol);
        gld16(&Bs[(cur ^ 1) * 4096 + it * 2048 + tid * 8], W + (size_t)(o0 + row) * CC + k0 + scol);
      }
    }
    bf16x8 af[4], bf[4];
    #pragma unroll
    for (int m = 0; m < 4; ++m) af[m] = *(const bf16x8*)&As[cur * 4096 + (wr + m * 16 + lr) * 32 + swz8];
    #pragma unroll
    for (int n = 0; n < 4; ++n) bf[n] = *(const bf16x8*)&Bs[cur * 4096 + (wc + n * 16 + lr) * 32 + swz8];
    #pragma unroll
    for (int m = 0; m < 4; ++m)
      #pragma unroll
      for (int n = 0; n < 4; ++n)
        acc[m][n] = __builtin_amdgcn_mfma_f32_16x16x32_bf16(af[m], bf[n], acc[m][n], 0, 0, 0);
    __syncthreads();
  }

  const int lq4 = (lane >> 4) * 4;
  #pragma unroll
  for (int m = 0; m < 4; ++m)
    #pragma unroll
    for (int r = 0; r < 4; ++r) {
      size_t row = (size_t)(m0 + wr + m * 16 + lq4 + r) * CC;
      #pragma unroll
      for (int n = 0; n < 4; ++n) {
        int o = o0 + wc + n * 16 + lr;
        Y[row + o] = f2b(acc[m][n][r] + bias[o]);
      }
    }
}

// 3 independent GEMMs (q,k,v) in one launch
__global__ __launch_bounds__(256) void gemm_tc3(
    const short* __restrict__ A0, const short* __restrict__ A1, const short* __restrict__ A2,
    const short* __restrict__ W0, const short* __restrict__ W1, const short* __restrict__ W2,
    const float* __restrict__ b0, const float* __restrict__ b1, const float* __restrict__ b2,
    short* __restrict__ Y0, short* __restrict__ Y1, short* __restrict__ Y2)
{
  __shared__ short As[2 * 4096];
  __shared__ short Bs[2 * 4096];
  const short *A, *W; const float* bias; short* Y;
  switch (blockIdx.y) {
    case 0:  A = A0; W = W0; bias = b0; Y = Y0; break;
    case 1:  A = A1; W = W1; bias = b1; Y = Y1; break;
    default: A = A2; W = W2; bias = b2; Y = Y2; break;
  }
  gemm_body(A, W, bias, Y, As, Bs, blockIdx.x, threadIdx.x);
}

__global__ __launch_bounds__(256) void gemm_tc(const short* __restrict__ A,
                                               const short* __restrict__ W,
                                               const float* __restrict__ bias,
                                               short* __restrict__ Y)
{
  __shared__ short As[2 * 4096];
  __shared__ short Bs[2 * 4096];
  gemm_body(A, W, bias, Y, As, Bs, blockIdx.x, threadIdx.x);
}

// ---------------------------------------------------------------------------
// Row feature kernel on [row][512] bf16, wave per row, in-place; all 3
// tensors in one launch (blockIdx.y = mode).
// mode 0=Q (rms->elu+1->per-head softmax->*8^-0.5)
//      1=K (rms->elu+1->EXP, masked rows -> 0)   [normalization deferred]
//      2=V (rms->elu+1->/64)
// ---------------------------------------------------------------------------
__global__ __launch_bounds__(256) void feat_all(short* __restrict__ qf, short* __restrict__ kf,
                                                short* __restrict__ vf,
                                                const float* __restrict__ gq,
                                                const float* __restrict__ gk,
                                                const float* __restrict__ gv,
                                                const unsigned char* __restrict__ mask)
{
  const int mode = blockIdx.y;
  short* buf = mode == 0 ? qf : (mode == 1 ? kf : vf);
  const float* g = mode == 0 ? gq : (mode == 1 ? gk : gv);
  const int row = blockIdx.x * 4 + (threadIdx.x >> 6);
  const int lane = threadIdx.x & 63;
  short* p = buf + (size_t)row * CC + lane * 8;
  if (mode == 1 && mask[row]) {            // whole (b,t) row masked -> exp = 0
    bf16x8 z = { 0,0,0,0,0,0,0,0 };
    *(bf16x8*)p = z;
    return;
  }
  bf16x8 v = *(const bf16x8*)p;
  float x[8], ss = 0.f;
  #pragma unroll
  for (int j = 0; j < 8; ++j) { x[j] = b2f(v[j]); ss += x[j] * x[j]; }
  #pragma unroll
  for (int off = 32; off; off >>= 1) ss += __shfl_xor(ss, off);
  float rn = rsqrtf(ss * (1.0f / CC) + EPS);
  float4 g0 = *(const float4*)(g + lane * 8);
  float4 g1 = *(const float4*)(g + lane * 8 + 4);
  float gv8[8] = { g0.x, g0.y, g0.z, g0.w, g1.x, g1.y, g1.z, g1.w };
  float f[8];
  #pragma unroll
  for (int j = 0; j < 8; ++j) {
    float t = x[j] * rn * gv8[j];
    f[j] = t > 0.f ? t + 1.f : __expf(t);
  }
  bf16x8 o;
  if (mode == 1) {
    #pragma unroll
    for (int j = 0; j < 8; ++j) o[j] = f2b(__expf(f[j]));   // unnormalized exp
  } else if (mode == 2) {
    #pragma unroll
    for (int j = 0; j < 8; ++j) o[j] = f2b(f[j] * (1.0f / DH));
  } else {  // Q: softmax over head (64 c = 8 lanes), no max-sub (f <= ~24)
    float ls = 0.f;
    #pragma unroll
    for (int j = 0; j < 8; ++j) { f[j] = __expf(f[j]); ls += f[j]; }
    ls += __shfl_xor(ls, 1); ls += __shfl_xor(ls, 2); ls += __shfl_xor(ls, 4);
    float sc = 0.35355339059327373f / ls;     // 8^-0.5 / sum
    #pragma unroll
    for (int j = 0; j < 8; ++j) o[j] = f2b(f[j] * sc);
  }
  *(bf16x8*)p = o;
}

// column-sum of kf_exp over t: S[b][c] = sum_t kfe[b][t][c]
__global__ __launch_bounds__(256) void ksm_sum(const short* __restrict__ kfe,
                                               float* __restrict__ S)
{
  const int b = blockIdx.y, tch = blockIdx.x;
  const int c2 = threadIdx.x * 2;
  float s0 = 0.f, s1 = 0.f;
  for (int t = 0; t < 128; ++t) {
    unsigned u = *(const unsigned*)&kfe[((size_t)b * TT + tch * 128 + t) * CC + c2];
    s0 += __uint_as_float(u << 16);
    s1 += __uint_as_float(u & 0xffff0000u);
  }
  atomicAdd(&S[b * CC + c2], s0);
  atomicAdd(&S[b * CC + c2 + 1], s1);
}

// ---------------------------------------------------------------------------
// ctx partials from t-major kfe/vf: P[tc][bh][q][v] = sum_t kfe[t][q]*vf[t][v]
// ---------------------------------------------------------------------------
__global__ __launch_bounds__(256) void ctx_t(const short* __restrict__ kf,
                                             const short* __restrict__ vf,
                                             float* __restrict__ P)
{
  __shared__ short Ks[64 * 64];
  __shared__ short Vs[64 * 64];
  const int tc = blockIdx.x, bh = blockIdx.y;
  const int b = bh >> 3, h = bh & 7;
  const int tid = threadIdx.x, wid = tid >> 6, lane = tid & 63;
  const int lr = lane & 15, lg = lane >> 4;
  f32x4 acc[4] = {};

  for (int ts = 0; ts < 8; ++ts) {
    #pragma unroll
    for (int i = 0; i < 2; ++i) {
      int n = i * 256 + tid;
      int t = n >> 3, ch = (n & 7) * 8;
      size_t src = ((size_t)b * TT + tc * 512 + ts * 64 + t) * CC + h * DH + ch;
      gld16(Ks + n * 8, kf + src);
      gld16(Vs + n * 8, vf + src);
    }
    __syncthreads();
    #pragma unroll
    for (int kk = 0; kk < 64; kk += 32) {
      short a[8];
      #pragma unroll
      for (int j = 0; j < 8; ++j)
        a[j] = Ks[(kk + lg * 8 + j) * 64 + wid * 16 + lr];
      bf16x8 af = *(const bf16x8*)&a[0];
      #pragma unroll
      for (int n = 0; n < 4; ++n) {
        short bv[8];
        #pragma unroll
        for (int j = 0; j < 8; ++j)
          bv[j] = Vs[(kk + lg * 8 + j) * 64 + n * 16 + lr];
        acc[n] = __builtin_amdgcn_mfma_f32_16x16x32_bf16(af, *(const bf16x8*)&bv[0],
                                                         acc[n], 0, 0, 0);
      }
    }
    __syncthreads();
  }
  float* pp = P + ((size_t)tc * 64 + bh) * (DH * DH);
  const int lq4 = lg * 4;
  #pragma unroll
  for (int n = 0; n < 4; ++n)
    #pragma unroll
    for (int r = 0; r < 4; ++r)
      pp[(wid * 16 + lq4 + r) * DH + n * 16 + lr] = acc[n][r];
}

// reduce chunk partials, apply 1/S (deferred k-softmax norm), emit CT[bh][v][q]
__global__ __launch_bounds__(256) void ctx_reduce(const float* __restrict__ P,
                                                  const float* __restrict__ S,
                                                  short* __restrict__ CT)
{
  int i = blockIdx.x * 256 + threadIdx.x;    // (bh, q, v), v fastest
  float s = 0.f;
  #pragma unroll
  for (int c = 0; c < 8; ++c) s += P[(size_t)c * 64 * DH * DH + i];
  int bh = i >> 12, rem = i & 4095, q = rem >> 6, v = rem & 63;
  int b = bh >> 3, h = bh & 7;
  float inv = 1.f / S[b * CC + h * DH + q];
  CT[((size_t)bh << 12) + v * 64 + q] = f2b(s * inv);
}

// ---------------------------------------------------------------------------
// attn: ao[row][h*64+v] = sum_q qf[row][h*64+q] * CT[bh][v][q]
// ---------------------------------------------------------------------------
__global__ __launch_bounds__(256) void attn_t(const short* __restrict__ qf,
                                              const short* __restrict__ CT,
                                              short* __restrict__ ao)
{
  __shared__ short As[128 * 72];
  __shared__ short Cs[64 * 72];
  const int m0 = blockIdx.x * 128, h = blockIdx.y;
  const int tid = threadIdx.x, wid = tid >> 6, lane = tid & 63;
  const int lr = lane & 15, lk8 = (lane >> 4) * 8;

  #pragma unroll
  for (int i = 0; i < 4; ++i) {
    int n = i * 256 + tid;
    int r = n >> 3, ch = (n & 7) * 8;
    *(bf16x8*)&As[r * 72 + ch] =
        *(const bf16x8*)(qf + (size_t)(m0 + r) * CC + h * DH + ch);
  }
  {
    const int bh0 = (m0 / TT) * 8 + h;
    #pragma unroll
    for (int i = 0; i < 2; ++i) {
      int n = i * 256 + tid;
      int v = n >> 3, ch = (n & 7) * 8;
      *(bf16x8*)&Cs[v * 72 + ch] = *(const bf16x8*)(CT + ((size_t)bh0 << 12) + v * 64 + ch);
    }
  }
  __syncthreads();

  const int wr = wid * 32;
  f32x4 acc[2][4] = {};
  #pragma unroll
  for (int kk = 0; kk < 64; kk += 32) {
    bf16x8 af[2], cf[4];
    #pragma unroll
    for (int m = 0; m < 2; ++m) af[m] = *(const bf16x8*)&As[(wr + m * 16 + lr) * 72 + kk + lk8];
    #pragma unroll
    for (int n = 0; n < 4; ++n) cf[n] = *(const bf16x8*)&Cs[(n * 16 + lr) * 72 + kk + lk8];
    #pragma unroll
    for (int m = 0; m < 2; ++m)
      #pragma unroll
      for (int n = 0; n < 4; ++n)
        acc[m][n] = __builtin_amdgcn_mfma_f32_16x16x32_bf16(af[m], cf[n], acc[m][n], 0, 0, 0);
  }
  const int lq4 = (lane >> 4) * 4;
  #pragma unroll
  for (int m = 0; m < 2; ++m)
    #pragma unroll
    for (int r = 0; r < 4; ++r) {
      size_t row = (size_t)(m0 + wr + m * 16 + lq4 + r) * CC + h * DH;
      #pragma unroll
      for (int n = 0; n < 4; ++n)
        ao[row + n * 16 + lr] = f2b(acc[m][n][r]);
    }
}

// ---------------------------------------------------------------------------
// fused final v2: single global read. Pass1 computes rms AND stores z=pj+qt
// as bf16 into LDS z[c][t] (stride 72, 16B-aligned rows). Pass2 reads z rows
// (b128, ~free), scales by rms[t]*g[c], coalesced float4 stores to [c][t].
// ---------------------------------------------------------------------------
__global__ __launch_bounds__(256) void final_fused(const short* __restrict__ pj,
                                                   const short* __restrict__ qt,
                                                   const float* __restrict__ g,
                                                   float* __restrict__ out)
{
  __shared__ short z[512 * 72];            // 72 KB
  __shared__ float rmss[64];
  const int t0 = blockIdx.x * 64, b = blockIdx.y;
  const int tid = threadIdx.x;

  // pass 1: thread = (t = tid>>2, 128-c range = (tid&3)*128)
  {
    const int t = tid >> 2, cb = (tid & 3) * 128;
    const size_t row = ((size_t)b * TT + t0 + t) * CC + cb;
    float ss = 0.f;
    #pragma unroll
    for (int j = 0; j < 16; ++j) {
      bf16x8 a = *(const bf16x8*)(pj + row + j * 8);
      bf16x8 q = *(const bf16x8*)(qt + row + j * 8);
      #pragma unroll
      for (int e = 0; e < 8; ++e) {
        float zf = b2f(a[e]) + b2f(q[e]);
        ss += zf * zf;
        z[(cb + j * 8 + e) * 72 + t] = f2b(zf);
      }
    }
    ss += __shfl_xor(ss, 1);
    ss += __shfl_xor(ss, 2);
    if ((tid & 3) == 0) rmss[t] = rsqrtf(ss * (1.0f / CC) + EPS);
  }
  __syncthreads();

  // pass 2: thread = (c-in-block = tid>>2, 16-t chunk = (tid&3)*16); 8 c-blocks
  const int c = tid >> 2, tcs = (tid & 3) * 16;
  #pragma unroll 1
  for (int cb8 = 0; cb8 < 8; ++cb8) {
    const int cc = cb8 * 64 + c;
    const float gc = g[cc];
    bf16x8 z0 = *(const bf16x8*)&z[cc * 72 + tcs];
    bf16x8 z1 = *(const bf16x8*)&z[cc * 72 + tcs + 8];
    float* dst = out + ((size_t)b * CC + cc) * TT + t0 + tcs;
    #pragma unroll
    for (int i = 0; i < 2; ++i) {
      float4 o0 = { b2f(z0[i*4+0]) * rmss[tcs+i*4+0] * gc, b2f(z0[i*4+1]) * rmss[tcs+i*4+1] * gc,
                    b2f(z0[i*4+2]) * rmss[tcs+i*4+2] * gc, b2f(z0[i*4+3]) * rmss[tcs+i*4+3] * gc };
      *(float4*)(dst + i * 4) = o0;
    }
    #pragma unroll
    for (int i = 0; i < 2; ++i) {
      float4 o1 = { b2f(z1[i*4+0]) * rmss[tcs+8+i*4+0] * gc, b2f(z1[i*4+1]) * rmss[tcs+8+i*4+1] * gc,
                    b2f(z1[i*4+2]) * rmss[tcs+8+i*4+2] * gc, b2f(z1[i*4+3]) * rmss[tcs+8+i*4+3] * gc };
      *(float4*)(dst + 8 + i * 4) = o1;
    }
  }
}

// ---------------------------------------------------------------------------
extern "C" void kernel_launch(void* const* d_in, const int* in_sizes, int n_in,
                              void* d_out, int out_size, void* d_ws, size_t ws_size,
                              hipStream_t stream) {
  (void)in_sizes; (void)n_in; (void)out_size; (void)ws_size;
  const float* queries = (const float*)d_in[0];
  const float* keys    = (const float*)d_in[1];
  const float* values  = (const float*)d_in[2];
  const unsigned char* mask = (const unsigned char*)d_in[3];
  const float* Wq = (const float*)d_in[4];
  const float* bq = (const float*)d_in[5];
  const float* gq = (const float*)d_in[6];
  const float* Wk = (const float*)d_in[7];
  const float* bk = (const float*)d_in[8];
  const float* gk = (const float*)d_in[9];
  const float* Wv = (const float*)d_in[10];
  const float* bv = (const float*)d_in[11];
  const float* gv = (const float*)d_in[12];
  const float* Wp = (const float*)d_in[13];
  const float* bp = (const float*)d_in[14];
  const float* g_out = (const float*)d_in[15];

  const size_t NCT = (size_t)NROWS * CC;       // 16,777,216 elements
  short* qt = (short*)d_ws;                    // bf16 [row][c] transposed inputs
  short* kt = qt + NCT;
  short* vt = kt + NCT;
  short* qf = vt + NCT;                        // gemm outputs / features (in-place)
  short* kf = qf + NCT;
  short* vf = kf + NCT;
  short* ao = kt;                              // reuse (kt dead after its gemm)
  short* pj = vt;                              // reuse (vt dead after its gemm)
  float* ctxP = (float*)(vf + NCT);            // 8 x 64 x 4096 fp32
  short* CT  = (short*)(ctxP + (size_t)8 * 64 * DH * DH);   // [bh][v][q] bf16
  short* wqb = CT + (size_t)64 * DH * DH;
  short* wkb = wqb + (size_t)CC * CC;
  short* wvb = wkb + (size_t)CC * CC;
  short* wpb = wvb + (size_t)CC * CC;
  float* S   = (float*)(wpb + (size_t)CC * CC);   // [B][C] softmax sums

  hipMemsetAsync(S, 0, (size_t)BB * CC * sizeof(float), stream);

  conv_w4<<<dim3(CC * CC / 2048, 4), 256, 0, stream>>>(Wq, Wk, Wv, Wp, wqb, wkb, wvb, wpb);

  transpose_cvt3<<<dim3(TT / 256, CC / 64, 3 * BB), 256, 0, stream>>>(
      queries, keys, values, qt, kt, vt);

  gemm_tc3<<<dim3(1024, 3), 256, 0, stream>>>(qt, kt, vt, wqb, wkb, wvb,
                                              bq, bk, bv, qf, kf, vf);

  feat_all<<<dim3(NROWS / 4, 3), 256, 0, stream>>>(qf, kf, vf, gq, gk, gv, mask);

  ksm_sum<<<dim3(32, BB), 256, 0, stream>>>(kf, S);

  ctx_t<<<dim3(8, BB * HH), 256, 0, stream>>>(kf, vf, ctxP);
  ctx_reduce<<<dim3(64 * DH * DH / 256), 256, 0, stream>>>(ctxP, S, CT);

  attn_t<<<dim3(NROWS / 128, HH), 256, 0, stream>>>(qf, CT, ao);

  gemm_tc<<<dim3(1024), 256, 0, stream>>>(ao, wpb, bp, pj);

  final_fused<<<dim3(TT / 64, BB), 256, 0, stream>>>(pj, qt, g_out, (float*)d_out);
}

// Round 10
// 315.391 us; speedup vs baseline: 1.5019x; 1.0125x over previous
//
#include <hip/hip_runtime.h>
#include <hip/hip_bf16.h>

// Problem constants (fixed by the reference)
#define BB 8
#define CC 512
#define TT 4096
#define HH 8
#define DH 64
#define EPS 1e-6f

#define NROWS (BB * TT)          // 32768 flat (b,t) rows

using bf16x8 = __attribute__((ext_vector_type(8))) short;
using s16x4  = __attribute__((ext_vector_type(4))) short;
using f32x4  = __attribute__((ext_vector_type(4))) float;

__device__ __forceinline__ short f2b(float f) {
  __hip_bfloat16 h = __float2bfloat16(f);
  return *reinterpret_cast<short*>(&h);
}
__device__ __forceinline__ float b2f(short s) {
  unsigned u = ((unsigned)(unsigned short)s) << 16;
  return __uint_as_float(u);
}

// async global->LDS 16B copy (dest must be wave-uniform base + lane*16)
__device__ __forceinline__ void gld16(short* lds_dst, const short* gsrc) {
  __builtin_amdgcn_global_load_lds(
      (const __attribute__((address_space(1))) unsigned int*)gsrc,
      (__attribute__((address_space(3))) unsigned int*)lds_dst, 16, 0, 0);
}

// 4 weights fp32 [o][c] -> bf16 [o][c], one launch
__global__ __launch_bounds__(256) void conv_w4(const float* __restrict__ s0, const float* __restrict__ s1,
                                               const float* __restrict__ s2, const float* __restrict__ s3,
                                               short* __restrict__ d0, short* __restrict__ d1,
                                               short* __restrict__ d2, short* __restrict__ d3)
{
  const float* src; short* dst;
  switch (blockIdx.y) {
    case 0: src = s0; dst = d0; break;
    case 1: src = s1; dst = d1; break;
    case 2: src = s2; dst = d2; break;
    default: src = s3; dst = d3; break;
  }
  int i8 = (blockIdx.x * 256 + threadIdx.x) * 8;
  float4 a = *(const float4*)(src + i8);
  float4 b = *(const float4*)(src + i8 + 4);
  bf16x8 h = { f2b(a.x), f2b(a.y), f2b(a.z), f2b(a.w),
               f2b(b.x), f2b(b.y), f2b(b.z), f2b(b.w) };
  *(bf16x8*)(dst + i8) = h;
}

// ---------------------------------------------------------------------------
// transpose+convert v3: X fp32 [b][c][t] -> Xt bf16 [b][t][c].
// grid (T/256, C/64, 3*B); per block 4 sub-tiles of 64t x 64c, double-buffered
// LDS, prefetch before the single barrier. Bank-conflict-free layout:
// row stride 120 shorts + pad(c) = ((c>>3)&7)*8  -> phase-B column gather is
// <=2-way (free); phase A at b64 minimum. Phase B reads short-PAIRS (b32 at
// even t), producing two output rows per thread: 8 b32 reads instead of 16 u16.
// ---------------------------------------------------------------------------
#define TSTR 120
__device__ __forceinline__ int tadr(int c, int t) {
  return c * TSTR + ((c >> 3) & 7) * 8 + t;
}

__global__ __launch_bounds__(256) void transpose_cvt3(const float* __restrict__ X0,
                                                      const float* __restrict__ X1,
                                                      const float* __restrict__ X2,
                                                      short* __restrict__ Y0,
                                                      short* __restrict__ Y1,
                                                      short* __restrict__ Y2)
{
  __shared__ short tile[2][64 * TSTR];
  const int t0 = blockIdx.x * 256, c0 = blockIdx.y * 64;
  const int b = blockIdx.z & 7, which = blockIdx.z >> 3;
  const float* X = which == 0 ? X0 : (which == 1 ? X1 : X2);
  short* Xt = which == 0 ? Y0 : (which == 1 ? Y1 : Y2);
  const int tid = threadIdx.x;
  const int cl = tid >> 4, t4 = (tid & 15) * 4;       // phase A coords
  const int T2 = (tid >> 3) * 2, ci = (tid & 7) * 8;  // phase B coords

  float4 r[4];
  #pragma unroll
  for (int it = 0; it < 4; ++it)
    r[it] = *(const float4*)(X + ((size_t)b * CC + c0 + it * 16 + cl) * TT + t0 + t4);

  for (int s = 0; s < 4; ++s) {
    const int cur = s & 1;
    #pragma unroll
    for (int it = 0; it < 4; ++it) {
      s16x4 h = { f2b(r[it].x), f2b(r[it].y), f2b(r[it].z), f2b(r[it].w) };
      *(s16x4*)&tile[cur][tadr(it * 16 + cl, t4)] = h;
    }
    if (s < 3) {
      #pragma unroll
      for (int it = 0; it < 4; ++it)
        r[it] = *(const float4*)(X + ((size_t)b * CC + c0 + it * 16 + cl) * TT
                                 + t0 + (s + 1) * 64 + t4);
    }
    __syncthreads();
    // phase B: each thread builds output rows T2 and T2+1, c range [ci, ci+8)
    unsigned u[8];
    #pragma unroll
    for (int i = 0; i < 8; ++i)
      u[i] = *(const unsigned*)&tile[cur][tadr(ci + i, T2)];
    short lo[8], hi[8];
    #pragma unroll
    for (int i = 0; i < 8; ++i) {
      lo[i] = (short)(u[i] & 0xffffu);
      hi[i] = (short)(u[i] >> 16);
    }
    short* dst0 = Xt + ((size_t)b * TT + t0 + s * 64 + T2) * CC + c0 + ci;
    *(bf16x8*)dst0 = *(bf16x8*)&lo[0];
    *(bf16x8*)(dst0 + CC) = *(bf16x8*)&hi[0];
    // single barrier per sub-tile is safe: a thread's LDS reads of buffer
    // cur^1 (iter s-1) happen-before it reaches iter-s's barrier, which
    // happens-before any thread's iter-s+1 writes to buffer cur^1.
  }
}

// ---------------------------------------------------------------------------
// GEMM body: Y[m][o] = sum_c A[m][c] * W[o][c] + bias[o]. 128x128, BK=32,
// double-buffered LDS, both-sides XOR swizzle, gld16 staging.
// ---------------------------------------------------------------------------
__device__ __forceinline__ void gemm_body(const short* __restrict__ A,
                                          const short* __restrict__ W,
                                          const float* __restrict__ bias,
                                          short* __restrict__ Y,
                                          short* As, short* Bs, int x, int tid)
{
  int wg = (x & 7) * 128 + (x >> 3);       // XCD-chunked
  const int m0 = (wg >> 2) * 128;          // 256 m-tiles
  const int o0 = (wg & 3) * 128;           // 4 o-tiles

  const int wid = tid >> 6, lane = tid & 63;
  const int wr = (wid >> 1) * 64, wc = (wid & 1) * 64;
  const int lr = lane & 15, g = lane >> 4;
  const int swz8 = (g ^ ((lr >> 1) & 3)) * 8;           // read-side swizzle

  const int srow0 = tid >> 2;                            // + it*64
  const int scol  = ((tid & 3) ^ ((tid >> 3) & 3)) * 8;  // source-side swizzle

  f32x4 acc[4][4] = {};

  #pragma unroll
  for (int it = 0; it < 2; ++it) {
    int row = it * 64 + srow0;
    gld16(&As[it * 2048 + tid * 8], A + (size_t)(m0 + row) * CC + scol);
    gld16(&Bs[it * 2048 + tid * 8], W + (size_t)(o0 + row) * CC + scol);
  }
  __syncthreads();

  for (int step = 0; step < 16; ++step) {
    const int cur = step & 1;
    if (step < 15) {
      const int k0 = (step + 1) * 32;
      #pragma unroll
      for (int it = 0; it < 2; ++it) {
        int row = it * 64 + srow0;
        gld16(&As[(cur ^ 1) * 4096 + it * 2048 + tid * 8], A + (size_t)(m0 + row) * CC + k0 + scol);
        gld16(&Bs[(cur ^ 1) * 4096 + it * 2048 + tid * 8], W + (size_t)(o0 + row) * CC + k0 + scol);
      }
    }
    bf16x8 af[4], bf[4];
    #pragma unroll
    for (int m = 0; m < 4; ++m) af[m] = *(const bf16x8*)&As[cur * 4096 + (wr + m * 16 + lr) * 32 + swz8];
    #pragma unroll
    for (int n = 0; n < 4; ++n) bf[n] = *(const bf16x8*)&Bs[cur * 4096 + (wc + n * 16 + lr) * 32 + swz8];
    #pragma unroll
    for (int m = 0; m < 4; ++m)
      #pragma unroll
      for (int n = 0; n < 4; ++n)
        acc[m][n] = __builtin_amdgcn_mfma_f32_16x16x32_bf16(af[m], bf[n], acc[m][n], 0, 0, 0);
    __syncthreads();
  }

  const int lq4 = (lane >> 4) * 4;
  #pragma unroll
  for (int m = 0; m < 4; ++m)
    #pragma unroll
    for (int r = 0; r < 4; ++r) {
      size_t row = (size_t)(m0 + wr + m * 16 + lq4 + r) * CC;
      #pragma unroll
      for (int n = 0; n < 4; ++n) {
        int o = o0 + wc + n * 16 + lr;
        Y[row + o] = f2b(acc[m][n][r] + bias[o]);
      }
    }
}

// 3 independent GEMMs (q,k,v) in one launch
__global__ __launch_bounds__(256) void gemm_tc3(
    const short* __restrict__ A0, const short* __restrict__ A1, const short* __restrict__ A2,
    const short* __restrict__ W0, const short* __restrict__ W1, const short* __restrict__ W2,
    const float* __restrict__ b0, const float* __restrict__ b1, const float* __restrict__ b2,
    short* __restrict__ Y0, short* __restrict__ Y1, short* __restrict__ Y2)
{
  __shared__ short As[2 * 4096];
  __shared__ short Bs[2 * 4096];
  const short *A, *W; const float* bias; short* Y;
  switch (blockIdx.y) {
    case 0:  A = A0; W = W0; bias = b0; Y = Y0; break;
    case 1:  A = A1; W = W1; bias = b1; Y = Y1; break;
    default: A = A2; W = W2; bias = b2; Y = Y2; break;
  }
  gemm_body(A, W, bias, Y, As, Bs, blockIdx.x, threadIdx.x);
}

__global__ __launch_bounds__(256) void gemm_tc(const short* __restrict__ A,
                                               const short* __restrict__ W,
                                               const float* __restrict__ bias,
                                               short* __restrict__ Y)
{
  __shared__ short As[2 * 4096];
  __shared__ short Bs[2 * 4096];
  gemm_body(A, W, bias, Y, As, Bs, blockIdx.x, threadIdx.x);
}

// ---------------------------------------------------------------------------
// Row feature kernel on [row][512] bf16, wave per row, in-place; all 3
// tensors in one launch (blockIdx.y = mode).
// mode 0=Q (rms->elu+1->per-head softmax->*8^-0.5)
//      1=K (rms->elu+1->EXP, masked rows -> 0)   [normalization deferred]
//      2=V (rms->elu+1->/64)
// ---------------------------------------------------------------------------
__global__ __launch_bounds__(256) void feat_all(short* __restrict__ qf, short* __restrict__ kf,
                                                short* __restrict__ vf,
                                                const float* __restrict__ gq,
                                                const float* __restrict__ gk,
                                                const float* __restrict__ gv,
                                                const unsigned char* __restrict__ mask)
{
  const int mode = blockIdx.y;
  short* buf = mode == 0 ? qf : (mode == 1 ? kf : vf);
  const float* g = mode == 0 ? gq : (mode == 1 ? gk : gv);
  const int row = blockIdx.x * 4 + (threadIdx.x >> 6);
  const int lane = threadIdx.x & 63;
  short* p = buf + (size_t)row * CC + lane * 8;
  if (mode == 1 && mask[row]) {            // whole (b,t) row masked -> exp = 0
    bf16x8 z = { 0,0,0,0,0,0,0,0 };
    *(bf16x8*)p = z;
    return;
  }
  bf16x8 v = *(const bf16x8*)p;
  float x[8], ss = 0.f;
  #pragma unroll
  for (int j = 0; j < 8; ++j) { x[j] = b2f(v[j]); ss += x[j] * x[j]; }
  #pragma unroll
  for (int off = 32; off; off >>= 1) ss += __shfl_xor(ss, off);
  float rn = rsqrtf(ss * (1.0f / CC) + EPS);
  float4 g0 = *(const float4*)(g + lane * 8);
  float4 g1 = *(const float4*)(g + lane * 8 + 4);
  float gv8[8] = { g0.x, g0.y, g0.z, g0.w, g1.x, g1.y, g1.z, g1.w };
  float f[8];
  #pragma unroll
  for (int j = 0; j < 8; ++j) {
    float t = x[j] * rn * gv8[j];
    f[j] = t > 0.f ? t + 1.f : __expf(t);
  }
  bf16x8 o;
  if (mode == 1) {
    #pragma unroll
    for (int j = 0; j < 8; ++j) o[j] = f2b(__expf(f[j]));   // unnormalized exp
  } else if (mode == 2) {
    #pragma unroll
    for (int j = 0; j < 8; ++j) o[j] = f2b(f[j] * (1.0f / DH));
  } else {  // Q: softmax over head (64 c = 8 lanes), no max-sub (f <= ~24)
    float ls = 0.f;
    #pragma unroll
    for (int j = 0; j < 8; ++j) { f[j] = __expf(f[j]); ls += f[j]; }
    ls += __shfl_xor(ls, 1); ls += __shfl_xor(ls, 2); ls += __shfl_xor(ls, 4);
    float sc = 0.35355339059327373f / ls;     // 8^-0.5 / sum
    #pragma unroll
    for (int j = 0; j < 8; ++j) o[j] = f2b(f[j] * sc);
  }
  *(bf16x8*)p = o;
}

// column-sum of kf_exp over t: S[b][c] = sum_t kfe[b][t][c]
__global__ __launch_bounds__(256) void ksm_sum(const short* __restrict__ kfe,
                                               float* __restrict__ S)
{
  const int b = blockIdx.y, tch = blockIdx.x;
  const int c2 = threadIdx.x * 2;
  float s0 = 0.f, s1 = 0.f;
  for (int t = 0; t < 128; ++t) {
    unsigned u = *(const unsigned*)&kfe[((size_t)b * TT + tch * 128 + t) * CC + c2];
    s0 += __uint_as_float(u << 16);
    s1 += __uint_as_float(u & 0xffff0000u);
  }
  atomicAdd(&S[b * CC + c2], s0);
  atomicAdd(&S[b * CC + c2 + 1], s1);
}

// ---------------------------------------------------------------------------
// ctx partials from t-major kfe/vf: P[tc][bh][q][v] = sum_t kfe[t][q]*vf[t][v]
// ---------------------------------------------------------------------------
__global__ __launch_bounds__(256) void ctx_t(const short* __restrict__ kf,
                                             const short* __restrict__ vf,
                                             float* __restrict__ P)
{
  __shared__ short Ks[64 * 64];
  __shared__ short Vs[64 * 64];
  const int tc = blockIdx.x, bh = blockIdx.y;
  const int b = bh >> 3, h = bh & 7;
  const int tid = threadIdx.x, wid = tid >> 6, lane = tid & 63;
  const int lr = lane & 15, lg = lane >> 4;
  f32x4 acc[4] = {};

  for (int ts = 0; ts < 8; ++ts) {
    #pragma unroll
    for (int i = 0; i < 2; ++i) {
      int n = i * 256 + tid;
      int t = n >> 3, ch = (n & 7) * 8;
      size_t src = ((size_t)b * TT + tc * 512 + ts * 64 + t) * CC + h * DH + ch;
      gld16(Ks + n * 8, kf + src);
      gld16(Vs + n * 8, vf + src);
    }
    __syncthreads();
    #pragma unroll
    for (int kk = 0; kk < 64; kk += 32) {
      short a[8];
      #pragma unroll
      for (int j = 0; j < 8; ++j)
        a[j] = Ks[(kk + lg * 8 + j) * 64 + wid * 16 + lr];
      bf16x8 af = *(const bf16x8*)&a[0];
      #pragma unroll
      for (int n = 0; n < 4; ++n) {
        short bv[8];
        #pragma unroll
        for (int j = 0; j < 8; ++j)
          bv[j] = Vs[(kk + lg * 8 + j) * 64 + n * 16 + lr];
        acc[n] = __builtin_amdgcn_mfma_f32_16x16x32_bf16(af, *(const bf16x8*)&bv[0],
                                                         acc[n], 0, 0, 0);
      }
    }
    __syncthreads();
  }
  float* pp = P + ((size_t)tc * 64 + bh) * (DH * DH);
  const int lq4 = lg * 4;
  #pragma unroll
  for (int n = 0; n < 4; ++n)
    #pragma unroll
    for (int r = 0; r < 4; ++r)
      pp[(wid * 16 + lq4 + r) * DH + n * 16 + lr] = acc[n][r];
}

// reduce chunk partials, apply 1/S (deferred k-softmax norm), emit CT[bh][v][q]
__global__ __launch_bounds__(256) void ctx_reduce(const float* __restrict__ P,
                                                  const float* __restrict__ S,
                                                  short* __restrict__ CT)
{
  int i = blockIdx.x * 256 + threadIdx.x;    // (bh, q, v), v fastest
  float s = 0.f;
  #pragma unroll
  for (int c = 0; c < 8; ++c) s += P[(size_t)c * 64 * DH * DH + i];
  int bh = i >> 12, rem = i & 4095, q = rem >> 6, v = rem & 63;
  int b = bh >> 3, h = bh & 7;
  float inv = 1.f / S[b * CC + h * DH + q];
  CT[((size_t)bh << 12) + v * 64 + q] = f2b(s * inv);
}

// ---------------------------------------------------------------------------
// attn: ao[row][h*64+v] = sum_q qf[row][h*64+q] * CT[bh][v][q]
// ---------------------------------------------------------------------------
__global__ __launch_bounds__(256) void attn_t(const short* __restrict__ qf,
                                              const short* __restrict__ CT,
                                              short* __restrict__ ao)
{
  __shared__ short As[128 * 72];
  __shared__ short Cs[64 * 72];
  const int m0 = blockIdx.x * 128, h = blockIdx.y;
  const int tid = threadIdx.x, wid = tid >> 6, lane = tid & 63;
  const int lr = lane & 15, lk8 = (lane >> 4) * 8;

  #pragma unroll
  for (int i = 0; i < 4; ++i) {
    int n = i * 256 + tid;
    int r = n >> 3, ch = (n & 7) * 8;
    *(bf16x8*)&As[r * 72 + ch] =
        *(const bf16x8*)(qf + (size_t)(m0 + r) * CC + h * DH + ch);
  }
  {
    const int bh0 = (m0 / TT) * 8 + h;
    #pragma unroll
    for (int i = 0; i < 2; ++i) {
      int n = i * 256 + tid;
      int v = n >> 3, ch = (n & 7) * 8;
      *(bf16x8*)&Cs[v * 72 + ch] = *(const bf16x8*)(CT + ((size_t)bh0 << 12) + v * 64 + ch);
    }
  }
  __syncthreads();

  const int wr = wid * 32;
  f32x4 acc[2][4] = {};
  #pragma unroll
  for (int kk = 0; kk < 64; kk += 32) {
    bf16x8 af[2], cf[4];
    #pragma unroll
    for (int m = 0; m < 2; ++m) af[m] = *(const bf16x8*)&As[(wr + m * 16 + lr) * 72 + kk + lk8];
    #pragma unroll
    for (int n = 0; n < 4; ++n) cf[n] = *(const bf16x8*)&Cs[(n * 16 + lr) * 72 + kk + lk8];
    #pragma unroll
    for (int m = 0; m < 2; ++m)
      #pragma unroll
      for (int n = 0; n < 4; ++n)
        acc[m][n] = __builtin_amdgcn_mfma_f32_16x16x32_bf16(af[m], cf[n], acc[m][n], 0, 0, 0);
  }
  const int lq4 = (lane >> 4) * 4;
  #pragma unroll
  for (int m = 0; m < 2; ++m)
    #pragma unroll
    for (int r = 0; r < 4; ++r) {
      size_t row = (size_t)(m0 + wr + m * 16 + lq4 + r) * CC + h * DH;
      #pragma unroll
      for (int n = 0; n < 4; ++n)
        ao[row + n * 16 + lr] = f2b(acc[m][n][r]);
    }
}

// ---------------------------------------------------------------------------
// fused final: single global read. Pass1 computes rms AND stores z=pj+qt
// as bf16 into LDS z[c][t] (stride 72, 16B-aligned rows). Pass2 reads z rows
// (b128), scales by rms[t]*g[c], coalesced float4 stores to [c][t].
// ---------------------------------------------------------------------------
__global__ __launch_bounds__(256) void final_fused(const short* __restrict__ pj,
                                                   const short* __restrict__ qt,
                                                   const float* __restrict__ g,
                                                   float* __restrict__ out)
{
  __shared__ short z[512 * 72];            // 72 KB
  __shared__ float rmss[64];
  const int t0 = blockIdx.x * 64, b = blockIdx.y;
  const int tid = threadIdx.x;

  // pass 1: thread = (t = tid>>2, 128-c range = (tid&3)*128)
  {
    const int t = tid >> 2, cb = (tid & 3) * 128;
    const size_t row = ((size_t)b * TT + t0 + t) * CC + cb;
    float ss = 0.f;
    #pragma unroll
    for (int j = 0; j < 16; ++j) {
      bf16x8 a = *(const bf16x8*)(pj + row + j * 8);
      bf16x8 q = *(const bf16x8*)(qt + row + j * 8);
      #pragma unroll
      for (int e = 0; e < 8; ++e) {
        float zf = b2f(a[e]) + b2f(q[e]);
        ss += zf * zf;
        z[(cb + j * 8 + e) * 72 + t] = f2b(zf);
      }
    }
    ss += __shfl_xor(ss, 1);
    ss += __shfl_xor(ss, 2);
    if ((tid & 3) == 0) rmss[t] = rsqrtf(ss * (1.0f / CC) + EPS);
  }
  __syncthreads();

  // pass 2: thread = (c-in-block = tid>>2, 16-t chunk = (tid&3)*16); 8 c-blocks
  const int c = tid >> 2, tcs = (tid & 3) * 16;
  #pragma unroll 1
  for (int cb8 = 0; cb8 < 8; ++cb8) {
    const int cc = cb8 * 64 + c;
    const float gc = g[cc];
    bf16x8 z0 = *(const bf16x8*)&z[cc * 72 + tcs];
    bf16x8 z1 = *(const bf16x8*)&z[cc * 72 + tcs + 8];
    float* dst = out + ((size_t)b * CC + cc) * TT + t0 + tcs;
    #pragma unroll
    for (int i = 0; i < 2; ++i) {
      float4 o0 = { b2f(z0[i*4+0]) * rmss[tcs+i*4+0] * gc, b2f(z0[i*4+1]) * rmss[tcs+i*4+1] * gc,
                    b2f(z0[i*4+2]) * rmss[tcs+i*4+2] * gc, b2f(z0[i*4+3]) * rmss[tcs+i*4+3] * gc };
      *(float4*)(dst + i * 4) = o0;
    }
    #pragma unroll
    for (int i = 0; i < 2; ++i) {
      float4 o1 = { b2f(z1[i*4+0]) * rmss[tcs+8+i*4+0] * gc, b2f(z1[i*4+1]) * rmss[tcs+8+i*4+1] * gc,
                    b2f(z1[i*4+2]) * rmss[tcs+8+i*4+2] * gc, b2f(z1[i*4+3]) * rmss[tcs+8+i*4+3] * gc };
      *(float4*)(dst + 8 + i * 4) = o1;
    }
  }
}

// ---------------------------------------------------------------------------
extern "C" void kernel_launch(void* const* d_in, const int* in_sizes, int n_in,
                              void* d_out, int out_size, void* d_ws, size_t ws_size,
                              hipStream_t stream) {
  (void)in_sizes; (void)n_in; (void)out_size; (void)ws_size;
  const float* queries = (const float*)d_in[0];
  const float* keys    = (const float*)d_in[1];
  const float* values  = (const float*)d_in[2];
  const unsigned char* mask = (const unsigned char*)d_in[3];
  const float* Wq = (const float*)d_in[4];
  const float* bq = (const float*)d_in[5];
  const float* gq = (const float*)d_in[6];
  const float* Wk = (const float*)d_in[7];
  const float* bk = (const float*)d_in[8];
  const float* gk = (const float*)d_in[9];
  const float* Wv = (const float*)d_in[10];
  const float* bv = (const float*)d_in[11];
  const float* gv = (const float*)d_in[12];
  const float* Wp = (const float*)d_in[13];
  const float* bp = (const float*)d_in[14];
  const float* g_out = (const float*)d_in[15];

  const size_t NCT = (size_t)NROWS * CC;       // 16,777,216 elements
  short* qt = (short*)d_ws;                    // bf16 [row][c] transposed inputs
  short* kt = qt + NCT;
  short* vt = kt + NCT;
  short* qf = vt + NCT;                        // gemm outputs / features (in-place)
  short* kf = qf + NCT;
  short* vf = kf + NCT;
  short* ao = kt;                              // reuse (kt dead after its gemm)
  short* pj = vt;                              // reuse (vt dead after its gemm)
  float* ctxP = (float*)(vf + NCT);            // 8 x 64 x 4096 fp32
  short* CT  = (short*)(ctxP + (size_t)8 * 64 * DH * DH);   // [bh][v][q] bf16
  short* wqb = CT + (size_t)64 * DH * DH;
  short* wkb = wqb + (size_t)CC * CC;
  short* wvb = wkb + (size_t)CC * CC;
  short* wpb = wvb + (size_t)CC * CC;
  float* S   = (float*)(wpb + (size_t)CC * CC);   // [B][C] softmax sums

  hipMemsetAsync(S, 0, (size_t)BB * CC * sizeof(float), stream);

  conv_w4<<<dim3(CC * CC / 2048, 4), 256, 0, stream>>>(Wq, Wk, Wv, Wp, wqb, wkb, wvb, wpb);

  transpose_cvt3<<<dim3(TT / 256, CC / 64, 3 * BB), 256, 0, stream>>>(
      queries, keys, values, qt, kt, vt);

  gemm_tc3<<<dim3(1024, 3), 256, 0, stream>>>(qt, kt, vt, wqb, wkb, wvb,
                                              bq, bk, bv, qf, kf, vf);

  feat_all<<<dim3(NROWS / 4, 3), 256, 0, stream>>>(qf, kf, vf, gq, gk, gv, mask);

  ksm_sum<<<dim3(32, BB), 256, 0, stream>>>(kf, S);

  ctx_t<<<dim3(8, BB * HH), 256, 0, stream>>>(kf, vf, ctxP);
  ctx_reduce<<<dim3(64 * DH * DH / 256), 256, 0, stream>>>(ctxP, S, CT);

  attn_t<<<dim3(NROWS / 128, HH), 256, 0, stream>>>(qf, CT, ao);

  gemm_tc<<<dim3(1024), 256, 0, stream>>>(ao, wpb, bp, pj);

  final_fused<<<dim3(TT / 64, BB), 256, 0, stream>>>(pj, qt, g_out, (float*)d_out);
}